// Round 1
// baseline (20131.377 us; speedup 1.0000x reference)
//
#include <hip/hip_runtime.h>
#include <math.h>

#define B_SZ 2048
#define SEQ 64
#define FIN 16
#define H 512
#define G4 2048   // 4*H
#define HH 256
#define NE 8
#define HOR 8

#define BM 128
#define BN 128
#define BK 16

// Generic fused GEMM: C[z] = act( A1 @ W1[z]^T + A2 @ W2^T + bias[z] )
// A1: (M,K1) row-major lda1; W1: (N,K1) row-major ldw1 (+ wz_stride per blockIdx.z)
// A2/W2 optional second K-source (K2 % BK == 0, or K2 == 0).
// M, N assumed multiples of BM, BN (true for all call sites).
__global__ __launch_bounds__(256)
void gemm_bias_kernel(
    const float* __restrict__ A1, int lda1, int K1,
    const float* __restrict__ W1, int ldw1, long wz_stride,
    const float* __restrict__ A2, int lda2, int K2,
    const float* __restrict__ W2, int ldw2,
    const float* __restrict__ bias, long bz_stride,
    float* __restrict__ C, int ldc, long cz_stride,
    int relu)
{
    __shared__ float sA[BK][BM + 4];
    __shared__ float sB[BK][BN + 4];
    const int z = blockIdx.z;
    const float* W1z = W1 + (long)z * wz_stride;
    const float* biasz = bias + (long)z * bz_stride;
    float* Cz = C + (long)z * cz_stride;

    const int tid = threadIdx.x;
    const int m0 = blockIdx.y * BM;
    const int n0 = blockIdx.x * BN;
    const int lrow = tid >> 2;          // 0..63
    const int lk4  = (tid & 3) << 2;    // 0,4,8,12
    const int ty = tid >> 4;            // 0..15
    const int tx = tid & 15;            // 0..15

    float acc[8][8];
    #pragma unroll
    for (int i = 0; i < 8; i++)
        #pragma unroll
        for (int j = 0; j < 8; j++) acc[i][j] = 0.f;

    const int K1t = (K1 + BK - 1) / BK;
    const int K2t = K2 / BK;
    const int KT = K1t + K2t;

    for (int kt = 0; kt < KT; ++kt) {
        const float* Asrc; const float* Wsrc; int Alda, Wldw, k0, Klim;
        if (kt < K1t) { Asrc = A1; Wsrc = W1z; Alda = lda1; Wldw = ldw1; k0 = kt * BK; Klim = K1; }
        else          { Asrc = A2; Wsrc = W2;  Alda = lda2; Wldw = ldw2; k0 = (kt - K1t) * BK; Klim = K2; }
        const int gk = k0 + lk4;
        #pragma unroll
        for (int half = 0; half < 2; ++half) {
            int r = lrow + half * 64;
            float4 va = make_float4(0.f, 0.f, 0.f, 0.f);
            float4 vw = make_float4(0.f, 0.f, 0.f, 0.f);
            if (gk + 4 <= Klim) {
                va = *reinterpret_cast<const float4*>(Asrc + (long)(m0 + r) * Alda + gk);
                vw = *reinterpret_cast<const float4*>(Wsrc + (long)(n0 + r) * Wldw + gk);
            } else if (gk < Klim) {
                const float* pa = Asrc + (long)(m0 + r) * Alda;
                const float* pw = Wsrc + (long)(n0 + r) * Wldw;
                float ta[4] = {0.f,0.f,0.f,0.f}, tw[4] = {0.f,0.f,0.f,0.f};
                for (int q = 0; q < 4; q++) if (gk + q < Klim) { ta[q] = pa[gk + q]; tw[q] = pw[gk + q]; }
                va = make_float4(ta[0], ta[1], ta[2], ta[3]);
                vw = make_float4(tw[0], tw[1], tw[2], tw[3]);
            }
            sA[lk4 + 0][r] = va.x; sA[lk4 + 1][r] = va.y; sA[lk4 + 2][r] = va.z; sA[lk4 + 3][r] = va.w;
            sB[lk4 + 0][r] = vw.x; sB[lk4 + 1][r] = vw.y; sB[lk4 + 2][r] = vw.z; sB[lk4 + 3][r] = vw.w;
        }
        __syncthreads();
        #pragma unroll
        for (int k = 0; k < BK; ++k) {
            float a[8], bb[8];
            *reinterpret_cast<float4*>(&a[0])  = *reinterpret_cast<const float4*>(&sA[k][ty * 8]);
            *reinterpret_cast<float4*>(&a[4])  = *reinterpret_cast<const float4*>(&sA[k][ty * 8 + 4]);
            *reinterpret_cast<float4*>(&bb[0]) = *reinterpret_cast<const float4*>(&sB[k][tx * 8]);
            *reinterpret_cast<float4*>(&bb[4]) = *reinterpret_cast<const float4*>(&sB[k][tx * 8 + 4]);
            #pragma unroll
            for (int i = 0; i < 8; i++)
                #pragma unroll
                for (int j = 0; j < 8; j++)
                    acc[i][j] = fmaf(a[i], bb[j], acc[i][j]);
        }
        __syncthreads();
    }

    #pragma unroll
    for (int i = 0; i < 8; i++) {
        long m = m0 + ty * 8 + i;
        #pragma unroll
        for (int j = 0; j < 8; j++) {
            int n = n0 + tx * 8 + j;
            float v = acc[i][j] + biasz[n];
            if (relu) v = fmaxf(v, 0.f);
            acc[i][j] = v;
        }
        #pragma unroll
        for (int j = 0; j < 8; j += 4)
            *reinterpret_cast<float4*>(&Cz[m * ldc + n0 + tx * 8 + j]) =
                *reinterpret_cast<const float4*>(&acc[i][j]);
    }
}

// Pointwise LSTM cell update from gate pre-activations Z (B, 4H), i|f|g|o blocks.
__global__ __launch_bounds__(256)
void lstm_cell_kernel(const float* __restrict__ Z, float* __restrict__ h, float* __restrict__ c)
{
    long idx = (long)blockIdx.x * 256 + threadIdx.x;   // b*H + u
    int b = (int)(idx >> 9);
    int u = (int)(idx & 511);
    const float* zb = Z + (long)b * G4;
    float zi = zb[u], zf = zb[512 + u], zg = zb[1024 + u], zo = zb[1536 + u];
    float si = 1.f / (1.f + expf(-zi));
    float sf = 1.f / (1.f + expf(-zf));
    float so = 1.f / (1.f + expf(-zo));
    float tg = tanhf(zg);
    float cn = fmaf(sf, c[idx], si * tg);
    float hn = so * tanhf(cn);
    c[idx] = cn;
    h[idx] = hn;
}

// Gate head: gates[b,:] = softmax(t1[b,:] @ gW2^T + gb2). One wave per batch row.
__global__ __launch_bounds__(64)
void gates_kernel(const float* __restrict__ t1, const float* __restrict__ gW2,
                  const float* __restrict__ gb2, float* __restrict__ gates)
{
    int b = blockIdx.x;
    int t = threadIdx.x;
    const float* t1b = t1 + (long)b * HH;
    float acc[NE];
    #pragma unroll
    for (int e = 0; e < NE; e++) acc[e] = 0.f;
    for (int j = t; j < HH; j += 64) {
        float xv = t1b[j];
        #pragma unroll
        for (int e = 0; e < NE; e++) acc[e] += gW2[e * HH + j] * xv;
    }
    #pragma unroll
    for (int e = 0; e < NE; e++) {
        float v = acc[e];
        for (int off = 32; off; off >>= 1) v += __shfl_xor(v, off, 64);
        acc[e] = v;
    }
    if (t == 0) {
        float mx = -1e30f;
        #pragma unroll
        for (int e = 0; e < NE; e++) { acc[e] += gb2[e]; mx = fmaxf(mx, acc[e]); }
        float s = 0.f;
        #pragma unroll
        for (int e = 0; e < NE; e++) { acc[e] = expf(acc[e] - mx); s += acc[e]; }
        float inv = 1.f / s;
        #pragma unroll
        for (int e = 0; e < NE; e++) gates[(long)b * NE + e] = acc[e] * inv;
    }
}

// Expert second layer + gate-weighted sum over experts for one branch.
// hdd: (E, B, HH); W2: (E, nout, HH); writes outA[b*strideA] (+outB for nout==2)
// and dec_in[b*4 + dec_slot (+1)].
__global__ __launch_bounds__(64)
void combine_kernel(const float* __restrict__ hdd, const float* __restrict__ gates,
                    const float* __restrict__ W2, const float* __restrict__ b2, int nout,
                    float* __restrict__ outA, int strideA,
                    float* __restrict__ outB, int strideB,
                    float* __restrict__ dec_in, int dec_slot)
{
    int b = blockIdx.x;
    int t = threadIdx.x;
    int e = t >> 3, r = t & 7;
    const float* hb = hdd + ((long)e * B_SZ + b) * HH;
    float a0 = 0.f, a1 = 0.f;
    for (int j = r * 32; j < r * 32 + 32; ++j) {
        float hv = hb[j];
        a0 += W2[(e * nout + 0) * HH + j] * hv;
        if (nout == 2) a1 += W2[(e * nout + 1) * HH + j] * hv;
    }
    #pragma unroll
    for (int off = 1; off < 8; off <<= 1) { a0 += __shfl_xor(a0, off, 64); a1 += __shfl_xor(a1, off, 64); }
    float g = gates[(long)b * NE + e];
    float v0 = (r == 0) ? (a0 + b2[e * nout + 0]) * g : 0.f;
    float v1 = (r == 0 && nout == 2) ? (a1 + b2[e * nout + 1]) * g : 0.f;
    #pragma unroll
    for (int off = 8; off < 64; off <<= 1) { v0 += __shfl_xor(v0, off, 64); v1 += __shfl_xor(v1, off, 64); }
    if (t == 0) {
        outA[(long)b * strideA] = v0;
        if (outB) outB[(long)b * strideB] = v1;
        dec_in[(long)b * 4 + dec_slot] = v0;
        if (nout == 2) dec_in[(long)b * 4 + dec_slot + 1] = v1;
    }
}

__global__ __launch_bounds__(256)
void gates_avg_kernel(const float* __restrict__ gates, float* __restrict__ gavg, int first)
{
    int i = blockIdx.x * 256 + threadIdx.x;  // b*NE + e
    float v = gates[i] * (1.f / HOR);
    if (!first) v += gavg[i];
    gavg[i] = v;
}

extern "C" void kernel_launch(void* const* d_in, const int* in_sizes, int n_in,
                              void* d_out, int out_size, void* d_ws, size_t ws_size,
                              hipStream_t stream)
{
    const float* x    = (const float*)d_in[0];
    const float* Wih0 = (const float*)d_in[1];
    const float* Whh0 = (const float*)d_in[2];
    const float* b0   = (const float*)d_in[3];
    const float* Wih1 = (const float*)d_in[4];
    const float* Whh1 = (const float*)d_in[5];
    const float* b1   = (const float*)d_in[6];
    const float* dWih = (const float*)d_in[7];
    const float* dWhh = (const float*)d_in[8];
    const float* db   = (const float*)d_in[9];
    const float* gW1  = (const float*)d_in[10];
    const float* gb1  = (const float*)d_in[11];
    const float* gW2  = (const float*)d_in[12];
    const float* gb2  = (const float*)d_in[13];
    const float* tW1  = (const float*)d_in[14];
    const float* tb1  = (const float*)d_in[15];
    const float* tW2  = (const float*)d_in[16];
    const float* tb2  = (const float*)d_in[17];
    const float* iW1  = (const float*)d_in[18];
    const float* ib1  = (const float*)d_in[19];
    const float* iW2  = (const float*)d_in[20];
    const float* ib2  = (const float*)d_in[21];
    const float* wW1  = (const float*)d_in[22];
    const float* wb1  = (const float*)d_in[23];
    const float* wW2  = (const float*)d_in[24];
    const float* wb2  = (const float*)d_in[25];

    float* out = (float*)d_out;
    float* ws  = (float*)d_ws;
    const long BH = (long)B_SZ * H;
    float* h0     = ws;
    float* c0     = h0 + BH;
    float* h1     = c0 + BH;
    float* c1     = h1 + BH;
    float* Z      = c1 + BH;                    // B * 4H
    float* t1     = Z + (long)B_SZ * G4;        // B * HH
    float* gates  = t1 + (long)B_SZ * HH;       // B * NE
    float* dec_in = gates + (long)B_SZ * NE;    // B * 4
    float* hdd    = dec_in + (long)B_SZ * 4;    // NE * B * HH (reused per branch)

    hipMemsetAsync(h0, 0, (size_t)(4 * BH) * sizeof(float), stream);
    hipMemsetAsync(dec_in, 0, (size_t)B_SZ * 4 * sizeof(float), stream);

    dim3 blk(256);
    dim3 gz(G4 / BN, B_SZ / BM, 1);     // (16,16)
    dim3 gt1(HH / BN, B_SZ / BM, 1);    // (2,16)
    dim3 ge(HH / BN, B_SZ / BM, NE);    // (2,16,8)
    dim3 gcell(B_SZ * H / 256);

    // ---------------- Encoder: 64 steps, layers pipelined step-by-step ----------
    for (int t = 0; t < SEQ; ++t) {
        gemm_bias_kernel<<<gz, blk, 0, stream>>>(x + (long)t * FIN, SEQ * FIN, FIN, Wih0, FIN, 0,
                                                 h0, H, H, Whh0, H, b0, 0, Z, G4, 0, 0);
        lstm_cell_kernel<<<gcell, blk, 0, stream>>>(Z, h0, c0);
        gemm_bias_kernel<<<gz, blk, 0, stream>>>(h0, H, H, Wih1, H, 0,
                                                 h1, H, H, Whh1, H, b1, 0, Z, G4, 0, 0);
        lstm_cell_kernel<<<gcell, blk, 0, stream>>>(Z, h1, c1);
    }

    // ---------------- Decoder: 8 steps -----------------------------------------
    for (int t = 0; t < HOR; ++t) {
        gemm_bias_kernel<<<gz, blk, 0, stream>>>(dec_in, 4, 4, dWih, 4, 0,
                                                 h1, H, H, dWhh, H, db, 0, Z, G4, 0, 0);
        lstm_cell_kernel<<<gcell, blk, 0, stream>>>(Z, h1, c1);

        gemm_bias_kernel<<<gt1, blk, 0, stream>>>(h1, H, H, gW1, H, 0,
                                                  nullptr, 0, 0, nullptr, 0, gb1, 0, t1, HH, 0, 1);
        gates_kernel<<<dim3(B_SZ), dim3(64), 0, stream>>>(t1, gW2, gb2, gates);
        gates_avg_kernel<<<dim3(B_SZ * NE / 256), blk, 0, stream>>>(gates, out + (long)32 * B_SZ, t == 0 ? 1 : 0);

        // track branch (2 outputs)
        gemm_bias_kernel<<<ge, blk, 0, stream>>>(h1, H, H, tW1, H, (long)HH * H,
                                                 nullptr, 0, 0, nullptr, 0, tb1, HH, hdd, HH, (long)B_SZ * HH, 1);
        combine_kernel<<<dim3(B_SZ), dim3(64), 0, stream>>>(hdd, gates, tW2, tb2, 2,
                                                 out + t, 16, out + 8 + t, 16, dec_in, 0);
        // intensity branch (1 output)
        gemm_bias_kernel<<<ge, blk, 0, stream>>>(h1, H, H, iW1, H, (long)HH * H,
                                                 nullptr, 0, 0, nullptr, 0, ib1, HH, hdd, HH, (long)B_SZ * HH, 1);
        combine_kernel<<<dim3(B_SZ), dim3(64), 0, stream>>>(hdd, gates, iW2, ib2, 1,
                                                 out + (long)16 * B_SZ + t, 8, nullptr, 0, dec_in, 2);
        // wind branch (1 output)
        gemm_bias_kernel<<<ge, blk, 0, stream>>>(h1, H, H, wW1, H, (long)HH * H,
                                                 nullptr, 0, 0, nullptr, 0, wb1, HH, hdd, HH, (long)B_SZ * HH, 1);
        combine_kernel<<<dim3(B_SZ), dim3(64), 0, stream>>>(hdd, gates, wW2, wb2, 1,
                                                 out + (long)24 * B_SZ + t, 8, nullptr, 0, dec_in, 3);
    }
}

// Round 2
// 3453.539 us; speedup vs baseline: 5.8292x; 5.8292x over previous
//
#include <hip/hip_runtime.h>
#include <math.h>

#define B_SZ 2048
#define SEQ 64
#define FIN 16
#define H 512
#define G4 2048
#define HH 256
#define NE 8
#define HOR 8

typedef _Float16 v8h __attribute__((ext_vector_type(8)));
typedef float v4f __attribute__((ext_vector_type(4)));

__device__ __forceinline__ void gld16(const void* g, void* l) {
    __builtin_amdgcn_global_load_lds((const __attribute__((address_space(1))) void*)g,
                                     (__attribute__((address_space(3))) void*)l, 16, 0, 0);
}
__device__ __forceinline__ v4f mfma16(v8h a, v8h b, v4f c) {
    return __builtin_amdgcn_mfma_f32_16x16x32_f16(a, b, c, 0, 0, 0);
}
__device__ __forceinline__ float rcp_(float x) { return __builtin_amdgcn_rcpf(x); }
__device__ __forceinline__ float sigf(float x) { return rcp_(1.f + __expf(-x)); }
__device__ __forceinline__ float tanhf_(float x) { return 1.f - 2.f * rcp_(1.f + __expf(2.f * x)); }

// ---------------------------------------------------------------------------
// Unified fp16 MFMA GEMM.  C = A @ W^T (+bias).  A:(M,K) lda; W:(N,K) ldw.
// BM=128, BN=64, BK=32; 256 threads = 4 waves, wave tile 64x32.
// CELL=1: N=2048 gate-interleaved (n'=4u+g); epilogue does LSTM cell:
//   c (fp32) updated in place, h written fp16 to 1-2 activation buffers,
//   optional x_{t+1} copy into xdst cols [512,528).
// CELL=0: epilogue bias(+relu), writes fp16 C (ldc, per-z stride cz).
// ---------------------------------------------------------------------------
template<int CELL>
__global__ __launch_bounds__(256, 2)
void gemm16(const _Float16* __restrict__ A, int lda,
            const _Float16* __restrict__ W, int ldw, long wz,
            const float* __restrict__ bias, int bz, int K,
            float* __restrict__ cst,
            _Float16* __restrict__ h1p, int h1s, int h1o,
            _Float16* __restrict__ h2p, int h2s, int h2o,
            const _Float16* __restrict__ xsrc, _Float16* __restrict__ xdst,
            _Float16* __restrict__ Cc, int ldc, long cz, int relu)
{
    __shared__ _Float16 sA[128 * 32];   // [row][k] 64B rows
    __shared__ _Float16 sB[64 * 32];
    const int tid = threadIdx.x;
    const int lane = tid & 63, wv = tid >> 6;
    const int m0 = blockIdx.y * 128, n0 = blockIdx.x * 64;
    const long z = blockIdx.z;
    const _Float16* Wz = W + z * wz;

    const int srow = lane >> 2, scol = (lane & 3) * 8;
    const _Float16* gA = A + (long)(m0 + wv * 32 + srow) * lda + scol;
    const _Float16* gB = Wz + (long)(n0 + wv * 16 + srow) * ldw + scol;
    _Float16* lA0 = sA + (wv * 32) * 32;
    _Float16* lA1 = sA + (wv * 32 + 16) * 32;
    _Float16* lB0 = sB + (wv * 16) * 32;

    const int wm = (wv & 1) * 64, wn = (wv >> 1) * 32;
    const int fr = lane & 15, fc = (lane >> 4) * 8;
    const int q4 = (lane >> 4) * 4;

    v4f acc[4][2];
    #pragma unroll
    for (int i = 0; i < 4; i++)
        #pragma unroll
        for (int j = 0; j < 2; j++) acc[i][j] = (v4f){0.f, 0.f, 0.f, 0.f};

    for (int k0 = 0; k0 < K; k0 += 32) {
        gld16(gA, lA0);
        gld16(gA + (long)16 * lda, lA1);
        gld16(gB, lB0);
        gA += 32; gB += 32;
        __syncthreads();   // drains vmcnt -> staged tiles visible
        v8h b0 = *(const v8h*)(sB + (wn + fr) * 32 + fc);
        v8h b1 = *(const v8h*)(sB + (wn + 16 + fr) * 32 + fc);
        #pragma unroll
        for (int mt = 0; mt < 4; ++mt) {
            v8h a = *(const v8h*)(sA + (wm + mt * 16 + fr) * 32 + fc);
            acc[mt][0] = mfma16(a, b0, acc[mt][0]);
            acc[mt][1] = mfma16(a, b1, acc[mt][1]);
        }
        __syncthreads();
    }

    if constexpr (CELL) {
        __shared__ float zb[128 * 68];
        #pragma unroll
        for (int mt = 0; mt < 4; ++mt)
            #pragma unroll
            for (int nt = 0; nt < 2; ++nt) {
                int col = wn + nt * 16 + fr;
                float bv = bias[n0 + col];
                #pragma unroll
                for (int r = 0; r < 4; ++r)
                    zb[(wm + mt * 16 + q4 + r) * 68 + col] = acc[mt][nt][r] + bv;
            }
        __syncthreads();
        const int row = tid >> 1, ub = (tid & 1) * 8;
        const long b = m0 + row;
        const int ug = blockIdx.x * 16 + ub;   // global hidden unit base (8-aligned)
        float* cp = cst + b * 512 + ug;
        float cv[8] __attribute__((aligned(16)));
        *(float4*)&cv[0] = *(const float4*)cp;
        *(float4*)&cv[4] = *(const float4*)(cp + 4);
        v8h hv;
        #pragma unroll
        for (int i = 0; i < 8; ++i) {
            const float* zz = &zb[row * 68 + (ub + i) * 4];
            float zi = zz[0], zf = zz[1], zg = zz[2], zo = zz[3];
            float cn = sigf(zf) * cv[i] + sigf(zi) * tanhf_(zg);
            cv[i] = cn;
            hv[i] = (_Float16)(sigf(zo) * tanhf_(cn));
        }
        *(float4*)cp = *(float4*)&cv[0];
        *(float4*)(cp + 4) = *(float4*)&cv[4];
        *(v8h*)(h1p + b * (long)h1s + h1o + ug) = hv;
        if (h2p) *(v8h*)(h2p + b * (long)h2s + h2o + ug) = hv;
        if (xsrc != nullptr && blockIdx.x == 0) {
            int rr = tid >> 1, hh = (tid & 1) * 8;
            *(v8h*)(xdst + (long)(m0 + rr) * 544 + 512 + hh) =
                *(const v8h*)(xsrc + (long)(m0 + rr) * 16 + hh);
        }
    } else {
        _Float16* Czp = Cc + z * cz;
        #pragma unroll
        for (int mt = 0; mt < 4; ++mt)
            #pragma unroll
            for (int nt = 0; nt < 2; ++nt) {
                int col = n0 + wn + nt * 16 + fr;
                float bv = bias[z * bz + col];
                #pragma unroll
                for (int r = 0; r < 4; ++r) {
                    float v = acc[mt][nt][r] + bv;
                    if (relu) v = fmaxf(v, 0.f);
                    Czp[(long)(m0 + wm + mt * 16 + q4 + r) * ldc + col] = (_Float16)v;
                }
            }
    }
}

// Gate head: softmax over experts + running gates_avg accumulation.
__global__ __launch_bounds__(64)
void gates_k(const _Float16* __restrict__ t1, const float* __restrict__ gW2,
             const float* __restrict__ gb2, float* __restrict__ gates,
             float* __restrict__ gavg, int first)
{
    int b = blockIdx.x, t = threadIdx.x;
    const _Float16* t1b = t1 + (long)b * HH;
    float acc[NE];
    #pragma unroll
    for (int e = 0; e < NE; e++) acc[e] = 0.f;
    for (int j = t; j < HH; j += 64) {
        float xv = (float)t1b[j];
        #pragma unroll
        for (int e = 0; e < NE; e++) acc[e] += gW2[e * HH + j] * xv;
    }
    #pragma unroll
    for (int e = 0; e < NE; e++) {
        float v = acc[e];
        for (int off = 32; off; off >>= 1) v += __shfl_xor(v, off, 64);
        acc[e] = v;
    }
    if (t == 0) {
        float mx = -1e30f;
        #pragma unroll
        for (int e = 0; e < NE; e++) { acc[e] += gb2[e]; mx = fmaxf(mx, acc[e]); }
        float s = 0.f;
        #pragma unroll
        for (int e = 0; e < NE; e++) { acc[e] = __expf(acc[e] - mx); s += acc[e]; }
        float inv = 1.f / s;
        #pragma unroll
        for (int e = 0; e < NE; e++) {
            float ge = acc[e] * inv;
            gates[(long)b * NE + e] = ge;
            float prev = first ? 0.f : gavg[(long)b * NE + e];
            gavg[(long)b * NE + e] = prev + ge * (1.f / HOR);
        }
    }
}

// Expert layer-2 + gated combine for all 3 branches (blockIdx.y).
__global__ __launch_bounds__(64)
void combine3(const _Float16* __restrict__ hdd, const float* __restrict__ gates,
              const float* __restrict__ tW2, const float* __restrict__ tb2,
              const float* __restrict__ iW2, const float* __restrict__ ib2,
              const float* __restrict__ wW2, const float* __restrict__ wb2,
              float* __restrict__ out, _Float16* __restrict__ ddst, int step)
{
    const int b = blockIdx.x, br = blockIdx.y, t = threadIdx.x;
    const float* W2; const float* b2; int nout;
    if (br == 0) { W2 = tW2; b2 = tb2; nout = 2; }
    else if (br == 1) { W2 = iW2; b2 = ib2; nout = 1; }
    else { W2 = wW2; b2 = wb2; nout = 1; }
    const int e = t >> 3, r = t & 7;
    const _Float16* hb = hdd + ((long)(br * 8 + e) * B_SZ + b) * HH;
    float a0 = 0.f, a1 = 0.f;
    for (int j = r * 32; j < r * 32 + 32; ++j) {
        float hv = (float)hb[j];
        a0 += W2[(e * nout + 0) * HH + j] * hv;
        if (nout == 2) a1 += W2[(e * nout + 1) * HH + j] * hv;
    }
    #pragma unroll
    for (int off = 1; off < 8; off <<= 1) { a0 += __shfl_xor(a0, off, 64); a1 += __shfl_xor(a1, off, 64); }
    float g = gates[(long)b * NE + e];
    float v0 = (r == 0) ? (a0 + b2[e * nout + 0]) * g : 0.f;
    float v1 = (r == 0 && nout == 2) ? (a1 + b2[e * nout + 1]) * g : 0.f;
    #pragma unroll
    for (int off = 8; off < 64; off <<= 1) { v0 += __shfl_xor(v0, off, 64); v1 += __shfl_xor(v1, off, 64); }
    if (t == 0) {
        if (br == 0) {
            out[(long)b * 16 + step] = v0;
            out[(long)b * 16 + 8 + step] = v1;
            ddst[(long)b * 544 + 512 + 0] = (_Float16)v0;
            ddst[(long)b * 544 + 512 + 1] = (_Float16)v1;
        } else if (br == 1) {
            out[(long)16 * B_SZ + (long)b * 8 + step] = v0;
            ddst[(long)b * 544 + 512 + 2] = (_Float16)v0;
        } else {
            out[(long)24 * B_SZ + (long)b * 8 + step] = v0;
            ddst[(long)b * 544 + 512 + 3] = (_Float16)v0;
        }
    }
}

// Build gate-interleaved fp16 cell weight: dst[4u+g][k] = k<K1 ? s1[g*512+u][k]
// : k<K1+K2 ? s2[g*512+u][k-K1] : 0.  Also interleaves the bias.
__global__ __launch_bounds__(256)
void prep_cellw(const float* __restrict__ s1, int K1, const float* __restrict__ s2, int K2,
                _Float16* __restrict__ dst, int KOUT,
                const float* __restrict__ bs, float* __restrict__ bd)
{
    int np = blockIdx.x;
    int u = np >> 2, g = np & 3;
    int srow = g * 512 + u;
    const float* r1 = s1 + (long)srow * K1;
    const float* r2 = s2 + (long)srow * K2;
    _Float16* d = dst + (long)np * KOUT;
    for (int k = threadIdx.x; k < KOUT; k += 256) {
        float v = 0.f;
        if (k < K1) v = r1[k];
        else if (k < K1 + K2) v = r2[k - K1];
        d[k] = (_Float16)v;
    }
    if (threadIdx.x == 0) bd[np] = bs[srow];
}

__global__ __launch_bounds__(256)
void cvt16(const float* __restrict__ s, _Float16* __restrict__ d, long n)
{
    long i = (long)blockIdx.x * 256 + threadIdx.x;
    if (i < n) d[i] = (_Float16)s[i];
}

__global__ __launch_bounds__(256)
void cat3(const float* __restrict__ a, const float* __restrict__ b,
          const float* __restrict__ c, float* __restrict__ d)
{
    int i = blockIdx.x * 256 + threadIdx.x;   // < 6144
    float v = (i < 2048) ? a[i] : (i < 4096) ? b[i - 2048] : c[i - 4096];
    d[i] = v;
}

// x (B,S,16) fp32 -> xT (S,B,16) fp16; also seeds act0a x-columns with x_0.
__global__ __launch_bounds__(256)
void prep_x(const float* __restrict__ x, _Float16* __restrict__ xT, _Float16* __restrict__ act00)
{
    long i = (long)blockIdx.x * 256 + threadIdx.x;  // < B*S*16
    int f = (int)(i & 15);
    long bs = i >> 4;
    int s = (int)(bs & 63);
    long b = bs >> 6;
    float v = x[i];
    xT[((long)s * B_SZ + b) * 16 + f] = (_Float16)v;
    if (s == 0) act00[b * 544 + 512 + f] = (_Float16)v;
}

extern "C" void kernel_launch(void* const* d_in, const int* in_sizes, int n_in,
                              void* d_out, int out_size, void* d_ws, size_t ws_size,
                              hipStream_t stream)
{
    const float* x    = (const float*)d_in[0];
    const float* Wih0 = (const float*)d_in[1];
    const float* Whh0 = (const float*)d_in[2];
    const float* b0   = (const float*)d_in[3];
    const float* Wih1 = (const float*)d_in[4];
    const float* Whh1 = (const float*)d_in[5];
    const float* b1   = (const float*)d_in[6];
    const float* dWih = (const float*)d_in[7];
    const float* dWhh = (const float*)d_in[8];
    const float* db   = (const float*)d_in[9];
    const float* gW1  = (const float*)d_in[10];
    const float* gb1  = (const float*)d_in[11];
    const float* gW2  = (const float*)d_in[12];
    const float* gb2  = (const float*)d_in[13];
    const float* tW1  = (const float*)d_in[14];
    const float* tb1  = (const float*)d_in[15];
    const float* tW2  = (const float*)d_in[16];
    const float* tb2  = (const float*)d_in[17];
    const float* iW1  = (const float*)d_in[18];
    const float* ib1  = (const float*)d_in[19];
    const float* iW2  = (const float*)d_in[20];
    const float* ib2  = (const float*)d_in[21];
    const float* wW1  = (const float*)d_in[22];
    const float* wb1  = (const float*)d_in[23];
    const float* wW2  = (const float*)d_in[24];
    const float* wb2  = (const float*)d_in[25];
    float* out = (float*)d_out;

    char* p = (char*)d_ws;
    auto alloc = [&](size_t bytes) { char* r = p; p += (bytes + 255) & ~255ULL; return r; };
    _Float16* xT    = (_Float16*)alloc((size_t)SEQ * B_SZ * 16 * 2);
    _Float16* act0a = (_Float16*)alloc((size_t)B_SZ * 544 * 2);
    _Float16* act0b = (_Float16*)alloc((size_t)B_SZ * 544 * 2);
    _Float16* act1a = (_Float16*)alloc((size_t)B_SZ * 1024 * 2);
    _Float16* act1b = (_Float16*)alloc((size_t)B_SZ * 1024 * 2);
    _Float16* actDa = (_Float16*)alloc((size_t)B_SZ * 544 * 2);
    _Float16* actDb = (_Float16*)alloc((size_t)B_SZ * 544 * 2);
    float*    c0    = (float*)alloc((size_t)B_SZ * 512 * 4);
    float*    c1    = (float*)alloc((size_t)B_SZ * 512 * 4);
    _Float16* Wc0   = (_Float16*)alloc((size_t)G4 * 544 * 2);
    _Float16* Wc1   = (_Float16*)alloc((size_t)G4 * 1024 * 2);
    _Float16* Wcd   = (_Float16*)alloc((size_t)G4 * 544 * 2);
    float*    b0i   = (float*)alloc((size_t)G4 * 4);
    float*    b1i   = (float*)alloc((size_t)G4 * 4);
    float*    bdi   = (float*)alloc((size_t)G4 * 4);
    _Float16* gW1h  = (_Float16*)alloc((size_t)HH * 512 * 2);
    _Float16* W1all = (_Float16*)alloc((size_t)24 * HH * 512 * 2);
    float*    b1all = (float*)alloc((size_t)24 * HH * 4);
    _Float16* t1    = (_Float16*)alloc((size_t)B_SZ * HH * 2);
    float*    gates = (float*)alloc((size_t)B_SZ * NE * 4);
    _Float16* hdd   = (_Float16*)alloc((size_t)24 * B_SZ * HH * 2);

    // zero init: activation buffers (h parts + pads + dec_in) and c-states
    hipMemsetAsync(act0a, 0, (size_t)B_SZ * 544 * 2, stream);
    hipMemsetAsync(act0b, 0, (size_t)B_SZ * 544 * 2, stream);
    hipMemsetAsync(act1a, 0, (size_t)B_SZ * 1024 * 2, stream);
    hipMemsetAsync(act1b, 0, (size_t)B_SZ * 1024 * 2, stream);
    hipMemsetAsync(actDa, 0, (size_t)B_SZ * 544 * 2, stream);
    hipMemsetAsync(actDb, 0, (size_t)B_SZ * 544 * 2, stream);
    hipMemsetAsync(c0, 0, (size_t)B_SZ * 512 * 4, stream);
    hipMemsetAsync(c1, 0, (size_t)B_SZ * 512 * 4, stream);

    // one-time weight prep (idempotent, every launch)
    prep_cellw<<<dim3(G4), dim3(256), 0, stream>>>(Whh0, 512, Wih0, 16, Wc0, 544, b0, b0i);
    prep_cellw<<<dim3(G4), dim3(256), 0, stream>>>(Wih1, 512, Whh1, 512, Wc1, 1024, b1, b1i);
    prep_cellw<<<dim3(G4), dim3(256), 0, stream>>>(dWhh, 512, dWih, 4, Wcd, 544, db, bdi);
    cvt16<<<dim3(512), dim3(256), 0, stream>>>(gW1, gW1h, (long)HH * 512);
    cvt16<<<dim3(4096), dim3(256), 0, stream>>>(tW1, W1all, (long)NE * HH * 512);
    cvt16<<<dim3(4096), dim3(256), 0, stream>>>(iW1, W1all + (long)NE * HH * 512, (long)NE * HH * 512);
    cvt16<<<dim3(4096), dim3(256), 0, stream>>>(wW1, W1all + (long)16 * HH * 512, (long)NE * HH * 512);
    cat3<<<dim3(24), dim3(256), 0, stream>>>(tb1, ib1, wb1, b1all);
    prep_x<<<dim3(8192), dim3(256), 0, stream>>>(x, xT, act0a);

    dim3 blk(256);
    dim3 gcell(32, 16, 1);
    dim3 ghead(4, 16, 1);
    dim3 gexp(4, 16, 24);

    // ----- encoder: 64 steps, both layers fused-cell GEMMs -----
    for (int t = 0; t < SEQ; ++t) {
        _Float16* a0r = (t & 1) ? act0b : act0a;
        _Float16* a0w = (t & 1) ? act0a : act0b;
        _Float16* a1r = (t & 1) ? act1b : act1a;
        _Float16* a1w = (t & 1) ? act1a : act1b;
        const _Float16* xs = (t < SEQ - 1) ? (xT + (long)(t + 1) * B_SZ * 16) : nullptr;
        // L0: reads [h0^{t-1} | x_t]; writes h0^t -> a0w (own next) + a1r (L1 this step); copies x_{t+1} -> a0w
        gemm16<1><<<gcell, blk, 0, stream>>>(a0r, 544, Wc0, 544, 0, b0i, 0, 544,
                                             c0, a0w, 544, 0, a1r, 1024, 0, xs, a0w,
                                             nullptr, 0, 0, 0);
        // L1: reads [h0^t | h1^{t-1}]; writes h1^t -> a1w cols[512:] + mirror actDa
        gemm16<1><<<gcell, blk, 0, stream>>>(a1r, 1024, Wc1, 1024, 0, b1i, 0, 1024,
                                             c1, a1w, 1024, 512, actDa, 544, 0, nullptr, nullptr,
                                             nullptr, 0, 0, 0);
    }

    // ----- decoder: 8 steps -----
    for (int t = 0; t < HOR; ++t) {
        _Float16* dr = (t & 1) ? actDb : actDa;
        _Float16* dw = (t & 1) ? actDa : actDb;
        gemm16<1><<<gcell, blk, 0, stream>>>(dr, 544, Wcd, 544, 0, bdi, 0, 544,
                                             c1, dw, 544, 0, nullptr, 0, 0, nullptr, nullptr,
                                             nullptr, 0, 0, 0);
        // heads read ctx = h^t (cols 0..512 of dw)
        gemm16<0><<<ghead, blk, 0, stream>>>(dw, 544, gW1h, 512, 0, gb1, 0, 512,
                                             nullptr, nullptr, 0, 0, nullptr, 0, 0, nullptr, nullptr,
                                             t1, 256, 0, 1);
        gemm16<0><<<gexp, blk, 0, stream>>>(dw, 544, W1all, 512, (long)HH * 512, b1all, 256, 512,
                                            nullptr, nullptr, 0, 0, nullptr, 0, 0, nullptr, nullptr,
                                            hdd, 256, (long)B_SZ * HH, 1);
        gates_k<<<dim3(B_SZ), dim3(64), 0, stream>>>(t1, gW2, gb2, gates,
                                                     out + (long)32 * B_SZ, t == 0 ? 1 : 0);
        combine3<<<dim3(B_SZ, 3), dim3(64), 0, stream>>>(hdd, gates, tW2, tb2, iW2, ib2, wW2, wb2,
                                                         out, dw, t);
    }
}

// Round 3
// 3027.402 us; speedup vs baseline: 6.6497x; 1.1408x over previous
//
#include <hip/hip_runtime.h>
#include <math.h>

#define B_SZ 2048
#define SEQ 64
#define FIN 16
#define H 512
#define G4 2048
#define HH 256
#define NE 8
#define HOR 8

typedef _Float16 v8h __attribute__((ext_vector_type(8)));
typedef _Float16 v4h __attribute__((ext_vector_type(4)));
typedef float v4f __attribute__((ext_vector_type(4)));

__device__ __forceinline__ void gld16(const void* g, void* l) {
    __builtin_amdgcn_global_load_lds((const __attribute__((address_space(1))) void*)g,
                                     (__attribute__((address_space(3))) void*)l, 16, 0, 0);
}
__device__ __forceinline__ v4f mfma16(v8h a, v8h b, v4f c) {
    return __builtin_amdgcn_mfma_f32_16x16x32_f16(a, b, c, 0, 0, 0);
}
__device__ __forceinline__ float rcp_(float x) { return __builtin_amdgcn_rcpf(x); }
__device__ __forceinline__ float sigf(float x) { return rcp_(1.f + __expf(-x)); }
__device__ __forceinline__ float tanhf_(float x) { return 1.f - 2.f * rcp_(1.f + __expf(2.f * x)); }

// ---------------------------------------------------------------------------
// Unified fp16 MFMA GEMM, double-buffered staging.
// C = A @ W^T (+bias).  A:(M,K) lda; W:(N,K) ldw.  BM=128 BN=64 BK=32.
// MODE 0: bias(+relu) -> fp16 C.          MODE 1: LSTM-cell epilogue.
// MODE 2: expert layer-2 partials: per-row dot with w2all, partials -> pe.
// ---------------------------------------------------------------------------
template<int MODE>
__global__ __launch_bounds__(256, 2)
void gemm16(const _Float16* __restrict__ A, int lda,
            const _Float16* __restrict__ W, int ldw, long wz,
            const float* __restrict__ bias, int bz, int K,
            float* __restrict__ cst,
            _Float16* __restrict__ h1p, int h1s, int h1o,
            _Float16* __restrict__ h2p, int h2s, int h2o,
            const _Float16* __restrict__ xsrc, _Float16* __restrict__ xdst,
            _Float16* __restrict__ Cc, int ldc, long cz, int relu,
            const float* __restrict__ w2all, float* __restrict__ pe)
{
    __shared__ _Float16 sA[2 * 128 * 32];
    __shared__ _Float16 sB[2 * 64 * 32];
    const int tid = threadIdx.x;
    const int lane = tid & 63, wv = tid >> 6;
    const int m0 = blockIdx.y * 128, n0 = blockIdx.x * 64;
    const long z = blockIdx.z;
    const _Float16* Wz = W + z * wz;

    const int srow = lane >> 2, scol = (lane & 3) * 8;
    const _Float16* gA = A + (long)(m0 + wv * 32 + srow) * lda + scol;
    const _Float16* gB = Wz + (long)(n0 + wv * 16 + srow) * ldw + scol;

    const int wm = (wv & 1) * 64, wn = (wv >> 1) * 32;
    const int fr = lane & 15, fc = (lane >> 4) * 8;
    const int q4 = (lane >> 4) * 4;

    v4f acc[4][2];
    #pragma unroll
    for (int i = 0; i < 4; i++)
        #pragma unroll
        for (int j = 0; j < 2; j++) acc[i][j] = (v4f){0.f, 0.f, 0.f, 0.f};

    const int KT = K >> 5;
    // prefetch tile 0 into buf 0
    {
        _Float16* dA = sA + wv * 32 * 32;
        gld16(gA, dA);
        gld16(gA + (long)16 * lda, dA + 16 * 32);
        gld16(gB, sB + wv * 16 * 32);
        gA += 32; gB += 32;
    }
    for (int kt = 0; kt < KT; ++kt) {
        __syncthreads();                    // waits tile-kt loads (vmcnt), syncs waves
        const int cur = kt & 1;
        if (kt + 1 < KT) {                  // prefetch kt+1 into other buffer
            _Float16* dA = sA + (cur ^ 1) * 4096 + wv * 32 * 32;
            gld16(gA, dA);
            gld16(gA + (long)16 * lda, dA + 16 * 32);
            gld16(gB, sB + (cur ^ 1) * 2048 + wv * 16 * 32);
            gA += 32; gB += 32;
        }
        const _Float16* cA = sA + cur * 4096;
        const _Float16* cB = sB + cur * 2048;
        v8h b0 = *(const v8h*)(cB + (wn + fr) * 32 + fc);
        v8h b1 = *(const v8h*)(cB + (wn + 16 + fr) * 32 + fc);
        #pragma unroll
        for (int mt = 0; mt < 4; ++mt) {
            v8h a = *(const v8h*)(cA + (wm + mt * 16 + fr) * 32 + fc);
            acc[mt][0] = mfma16(a, b0, acc[mt][0]);
            acc[mt][1] = mfma16(a, b1, acc[mt][1]);
        }
    }
    __syncthreads();

    if constexpr (MODE == 1) {
        __shared__ float zb[128 * 68];
        #pragma unroll
        for (int mt = 0; mt < 4; ++mt)
            #pragma unroll
            for (int nt = 0; nt < 2; ++nt) {
                int col = wn + nt * 16 + fr;
                float bv = bias[n0 + col];
                #pragma unroll
                for (int r = 0; r < 4; ++r)
                    zb[(wm + mt * 16 + q4 + r) * 68 + col] = acc[mt][nt][r] + bv;
            }
        __syncthreads();
        const int row = tid >> 1, ub = (tid & 1) * 8;
        const long b = m0 + row;
        const int ug = blockIdx.x * 16 + ub;
        float* cp = cst + b * 512 + ug;
        float cv[8] __attribute__((aligned(16)));
        *(float4*)&cv[0] = *(const float4*)cp;
        *(float4*)&cv[4] = *(const float4*)(cp + 4);
        v8h hv;
        #pragma unroll
        for (int i = 0; i < 8; ++i) {
            const float* zz = &zb[row * 68 + (ub + i) * 4];
            float zi = zz[0], zf = zz[1], zg = zz[2], zo = zz[3];
            float cn = sigf(zf) * cv[i] + sigf(zi) * tanhf_(zg);
            cv[i] = cn;
            hv[i] = (_Float16)(sigf(zo) * tanhf_(cn));
        }
        *(float4*)cp = *(float4*)&cv[0];
        *(float4*)(cp + 4) = *(float4*)&cv[4];
        *(v8h*)(h1p + b * (long)h1s + h1o + ug) = hv;
        if (h2p) *(v8h*)(h2p + b * (long)h2s + h2o + ug) = hv;
        if (xsrc != nullptr && blockIdx.x == 0) {
            int rr = tid >> 1, hh = (tid & 1) * 8;
            *(v8h*)(xdst + (long)(m0 + rr) * 544 + 512 + hh) =
                *(const v8h*)(xsrc + (long)(m0 + rr) * 16 + hh);
        }
    } else if constexpr (MODE == 2) {
        __shared__ float red[2][128][2];
        float w0[2], w1[2], bv[2];
        #pragma unroll
        for (int nt = 0; nt < 2; ++nt) {
            int colg = n0 + wn + nt * 16 + fr;
            w0[nt] = w2all[((long)z * 2 + 0) * 256 + colg];
            w1[nt] = w2all[((long)z * 2 + 1) * 256 + colg];
            bv[nt] = bias[z * bz + colg];
        }
        float p0[4][4], p1[4][4];
        #pragma unroll
        for (int mt = 0; mt < 4; ++mt)
            #pragma unroll
            for (int r = 0; r < 4; ++r) { p0[mt][r] = 0.f; p1[mt][r] = 0.f; }
        #pragma unroll
        for (int mt = 0; mt < 4; ++mt)
            #pragma unroll
            for (int nt = 0; nt < 2; ++nt)
                #pragma unroll
                for (int r = 0; r < 4; ++r) {
                    float v = fmaxf(acc[mt][nt][r] + bv[nt], 0.f);
                    p0[mt][r] = fmaf(v, w0[nt], p0[mt][r]);
                    p1[mt][r] = fmaf(v, w1[nt], p1[mt][r]);
                }
        #pragma unroll
        for (int off = 1; off < 16; off <<= 1)
            #pragma unroll
            for (int mt = 0; mt < 4; ++mt)
                #pragma unroll
                for (int r = 0; r < 4; ++r) {
                    p0[mt][r] += __shfl_xor(p0[mt][r], off, 64);
                    p1[mt][r] += __shfl_xor(p1[mt][r], off, 64);
                }
        if ((lane & 15) == 0) {
            #pragma unroll
            for (int mt = 0; mt < 4; ++mt)
                #pragma unroll
                for (int r = 0; r < 4; ++r) {
                    int row = wm + mt * 16 + q4 + r;
                    red[wv >> 1][row][0] = p0[mt][r];
                    red[wv >> 1][row][1] = p1[mt][r];
                }
        }
        __syncthreads();
        if (tid < 128) {
            #pragma unroll
            for (int o = 0; o < 2; ++o) {
                float v = red[0][tid][o] + red[1][tid][o];
                pe[(((long)blockIdx.x * 24 + z) * 2 + o) * 2048 + m0 + tid] = v;
            }
        }
    } else {
        _Float16* Czp = Cc + z * cz;
        #pragma unroll
        for (int mt = 0; mt < 4; ++mt)
            #pragma unroll
            for (int nt = 0; nt < 2; ++nt) {
                int col = n0 + wn + nt * 16 + fr;
                float bv = bias[z * bz + col];
                #pragma unroll
                for (int r = 0; r < 4; ++r) {
                    float v = acc[mt][nt][r] + bv;
                    if (relu) v = fmaxf(v, 0.f);
                    Czp[(long)(m0 + wm + mt * 16 + q4 + r) * ldc + col] = (_Float16)v;
                }
            }
    }
}

// Gate head: one wave per batch row, 4 rows/block.
__global__ __launch_bounds__(256)
void gates_k(const _Float16* __restrict__ t1, const float* __restrict__ gW2,
             const float* __restrict__ gb2, float* __restrict__ gates,
             float* __restrict__ gavg, int first)
{
    const int w = threadIdx.x >> 6, lane = threadIdx.x & 63;
    const int b = blockIdx.x * 4 + w;
    v4h xv = *(const v4h*)(t1 + (long)b * HH + lane * 4);
    float x0 = xv[0], x1 = xv[1], x2 = xv[2], x3 = xv[3];
    float acc[NE];
    #pragma unroll
    for (int e = 0; e < NE; e++) {
        const float* w2 = gW2 + e * HH + lane * 4;
        acc[e] = x0 * w2[0] + x1 * w2[1] + x2 * w2[2] + x3 * w2[3];
    }
    #pragma unroll
    for (int off = 1; off < 64; off <<= 1)
        #pragma unroll
        for (int e = 0; e < NE; e++) acc[e] += __shfl_xor(acc[e], off, 64);
    if (lane == 0) {
        float mx = -1e30f;
        #pragma unroll
        for (int e = 0; e < NE; e++) { acc[e] += gb2[e]; mx = fmaxf(mx, acc[e]); }
        float s = 0.f;
        #pragma unroll
        for (int e = 0; e < NE; e++) { acc[e] = __expf(acc[e] - mx); s += acc[e]; }
        float inv = 1.f / s;
        #pragma unroll
        for (int e = 0; e < NE; e++) {
            float ge = acc[e] * inv;
            gates[(long)b * NE + e] = ge;
            float prev = first ? 0.f : gavg[(long)b * NE + e];
            gavg[(long)b * NE + e] = prev + ge * (1.f / HOR);
        }
    }
}

// Final gate-weighted combine of expert partials; writes outputs + dec_in.
__global__ __launch_bounds__(256)
void finalize_k(const float* __restrict__ pe, const float* __restrict__ gates,
                const float* __restrict__ tb2, const float* __restrict__ ib2,
                const float* __restrict__ wb2,
                float* __restrict__ out, _Float16* __restrict__ dw, int step)
{
    const int b = blockIdx.x * 256 + threadIdx.x;   // < 2048
    float t0 = 0.f, t1v = 0.f, iv = 0.f, wvv = 0.f;
    #pragma unroll
    for (int e = 0; e < NE; e++) {
        float g = gates[(long)b * NE + e];
        float s00 = 0.f, s01 = 0.f, s10 = 0.f, s20 = 0.f;
        #pragma unroll
        for (int nb = 0; nb < 4; ++nb) {
            long base0 = (((long)nb * 24 + e) * 2) * 2048 + b;
            s00 += pe[base0];
            s01 += pe[base0 + 2048];
            s10 += pe[(((long)nb * 24 + 8 + e) * 2) * 2048 + b];
            s20 += pe[(((long)nb * 24 + 16 + e) * 2) * 2048 + b];
        }
        t0  += g * (s00 + tb2[e * 2 + 0]);
        t1v += g * (s01 + tb2[e * 2 + 1]);
        iv  += g * (s10 + ib2[e]);
        wvv += g * (s20 + wb2[e]);
    }
    out[(long)b * 16 + step] = t0;
    out[(long)b * 16 + 8 + step] = t1v;
    out[(long)16 * B_SZ + (long)b * 8 + step] = iv;
    out[(long)24 * B_SZ + (long)b * 8 + step] = wvv;
    _Float16* d = dw + (long)b * 544 + 512;
    d[0] = (_Float16)t0; d[1] = (_Float16)t1v; d[2] = (_Float16)iv; d[3] = (_Float16)wvv;
}

// Build gate-interleaved fp16 cell weight + bias.
__global__ __launch_bounds__(256)
void prep_cellw(const float* __restrict__ s1, int K1, const float* __restrict__ s2, int K2,
                _Float16* __restrict__ dst, int KOUT,
                const float* __restrict__ bs, float* __restrict__ bd)
{
    int np = blockIdx.x;
    int u = np >> 2, g = np & 3;
    int srow = g * 512 + u;
    const float* r1 = s1 + (long)srow * K1;
    const float* r2 = s2 + (long)srow * K2;
    _Float16* d = dst + (long)np * KOUT;
    for (int k = threadIdx.x; k < KOUT; k += 256) {
        float v = 0.f;
        if (k < K1) v = r1[k];
        else if (k < K1 + K2) v = r2[k - K1];
        d[k] = (_Float16)v;
    }
    if (threadIdx.x == 0) bd[np] = bs[srow];
}

__global__ __launch_bounds__(256)
void cvt16(const float* __restrict__ s, _Float16* __restrict__ d, long n)
{
    long i = (long)blockIdx.x * 256 + threadIdx.x;
    if (i < n) d[i] = (_Float16)s[i];
}

__global__ __launch_bounds__(256)
void cat3(const float* __restrict__ a, const float* __restrict__ b,
          const float* __restrict__ c, float* __restrict__ d)
{
    int i = blockIdx.x * 256 + threadIdx.x;   // < 6144
    float v = (i < 2048) ? a[i] : (i < 4096) ? b[i - 2048] : c[i - 4096];
    d[i] = v;
}

// Pack layer-2 expert weights: W2all[z][o][j], zeros for missing outputs.
__global__ __launch_bounds__(256)
void prep_w2(const float* __restrict__ tW2, const float* __restrict__ iW2,
             const float* __restrict__ wW2, float* __restrict__ W2all)
{
    int i = blockIdx.x * 256 + threadIdx.x;   // < 24*2*256
    int j = i & 255, o = (i >> 8) & 1, zz = i >> 9;
    int br = zz >> 3, e = zz & 7;
    float v = 0.f;
    if (br == 0) v = tW2[(e * 2 + o) * 256 + j];
    else if (o == 0) v = (br == 1 ? iW2 : wW2)[e * 256 + j];
    W2all[i] = v;
}

// x (B,S,16) fp32 -> xT (S,B,16) fp16; seeds act0a x-columns with x_0.
__global__ __launch_bounds__(256)
void prep_x(const float* __restrict__ x, _Float16* __restrict__ xT, _Float16* __restrict__ act00)
{
    long i = (long)blockIdx.x * 256 + threadIdx.x;
    int f = (int)(i & 15);
    long bs = i >> 4;
    int s = (int)(bs & 63);
    long b = bs >> 6;
    float v = x[i];
    xT[((long)s * B_SZ + b) * 16 + f] = (_Float16)v;
    if (s == 0) act00[b * 544 + 512 + f] = (_Float16)v;
}

extern "C" void kernel_launch(void* const* d_in, const int* in_sizes, int n_in,
                              void* d_out, int out_size, void* d_ws, size_t ws_size,
                              hipStream_t stream)
{
    const float* x    = (const float*)d_in[0];
    const float* Wih0 = (const float*)d_in[1];
    const float* Whh0 = (const float*)d_in[2];
    const float* b0   = (const float*)d_in[3];
    const float* Wih1 = (const float*)d_in[4];
    const float* Whh1 = (const float*)d_in[5];
    const float* b1   = (const float*)d_in[6];
    const float* dWih = (const float*)d_in[7];
    const float* dWhh = (const float*)d_in[8];
    const float* db   = (const float*)d_in[9];
    const float* gW1  = (const float*)d_in[10];
    const float* gb1  = (const float*)d_in[11];
    const float* gW2  = (const float*)d_in[12];
    const float* gb2  = (const float*)d_in[13];
    const float* tW1  = (const float*)d_in[14];
    const float* tb1  = (const float*)d_in[15];
    const float* tW2  = (const float*)d_in[16];
    const float* tb2  = (const float*)d_in[17];
    const float* iW1  = (const float*)d_in[18];
    const float* ib1  = (const float*)d_in[19];
    const float* iW2  = (const float*)d_in[20];
    const float* ib2  = (const float*)d_in[21];
    const float* wW1  = (const float*)d_in[22];
    const float* wb1  = (const float*)d_in[23];
    const float* wW2  = (const float*)d_in[24];
    const float* wb2  = (const float*)d_in[25];
    float* out = (float*)d_out;

    char* p = (char*)d_ws;
    auto alloc = [&](size_t bytes) { char* r = p; p += (bytes + 255) & ~255ULL; return r; };
    _Float16* xT    = (_Float16*)alloc((size_t)SEQ * B_SZ * 16 * 2);
    _Float16* act0a = (_Float16*)alloc((size_t)B_SZ * 544 * 2);
    _Float16* act0b = (_Float16*)alloc((size_t)B_SZ * 544 * 2);
    _Float16* act1a = (_Float16*)alloc((size_t)B_SZ * 1024 * 2);
    _Float16* act1b = (_Float16*)alloc((size_t)B_SZ * 1024 * 2);
    _Float16* actDa = (_Float16*)alloc((size_t)B_SZ * 544 * 2);
    _Float16* actDb = (_Float16*)alloc((size_t)B_SZ * 544 * 2);
    float*    c0    = (float*)alloc((size_t)B_SZ * 512 * 4);
    float*    c1    = (float*)alloc((size_t)B_SZ * 512 * 4);
    _Float16* Wc0   = (_Float16*)alloc((size_t)G4 * 544 * 2);
    _Float16* Wc1   = (_Float16*)alloc((size_t)G4 * 1024 * 2);
    _Float16* Wcd   = (_Float16*)alloc((size_t)G4 * 544 * 2);
    float*    b0i   = (float*)alloc((size_t)G4 * 4);
    float*    b1i   = (float*)alloc((size_t)G4 * 4);
    float*    bdi   = (float*)alloc((size_t)G4 * 4);
    _Float16* gW1h  = (_Float16*)alloc((size_t)HH * 512 * 2);
    _Float16* W1all = (_Float16*)alloc((size_t)24 * HH * 512 * 2);
    float*    b1all = (float*)alloc((size_t)24 * HH * 4);
    float*    W2all = (float*)alloc((size_t)24 * 2 * 256 * 4);
    _Float16* t1    = (_Float16*)alloc((size_t)B_SZ * HH * 2);
    float*    gates = (float*)alloc((size_t)B_SZ * NE * 4);
    float*    pe    = (float*)alloc((size_t)4 * 24 * 2 * 2048 * 4);

    hipMemsetAsync(act0a, 0, (size_t)B_SZ * 544 * 2, stream);
    hipMemsetAsync(act0b, 0, (size_t)B_SZ * 544 * 2, stream);
    hipMemsetAsync(act1a, 0, (size_t)B_SZ * 1024 * 2, stream);
    hipMemsetAsync(act1b, 0, (size_t)B_SZ * 1024 * 2, stream);
    hipMemsetAsync(actDa, 0, (size_t)B_SZ * 544 * 2, stream);
    hipMemsetAsync(actDb, 0, (size_t)B_SZ * 544 * 2, stream);
    hipMemsetAsync(c0, 0, (size_t)B_SZ * 512 * 4, stream);
    hipMemsetAsync(c1, 0, (size_t)B_SZ * 512 * 4, stream);

    prep_cellw<<<dim3(G4), dim3(256), 0, stream>>>(Whh0, 512, Wih0, 16, Wc0, 544, b0, b0i);
    prep_cellw<<<dim3(G4), dim3(256), 0, stream>>>(Wih1, 512, Whh1, 512, Wc1, 1024, b1, b1i);
    prep_cellw<<<dim3(G4), dim3(256), 0, stream>>>(dWhh, 512, dWih, 4, Wcd, 544, db, bdi);
    cvt16<<<dim3(512), dim3(256), 0, stream>>>(gW1, gW1h, (long)HH * 512);
    cvt16<<<dim3(4096), dim3(256), 0, stream>>>(tW1, W1all, (long)NE * HH * 512);
    cvt16<<<dim3(4096), dim3(256), 0, stream>>>(iW1, W1all + (long)NE * HH * 512, (long)NE * HH * 512);
    cvt16<<<dim3(4096), dim3(256), 0, stream>>>(wW1, W1all + (long)16 * HH * 512, (long)NE * HH * 512);
    cat3<<<dim3(24), dim3(256), 0, stream>>>(tb1, ib1, wb1, b1all);
    prep_w2<<<dim3(48), dim3(256), 0, stream>>>(tW2, iW2, wW2, W2all);
    prep_x<<<dim3(8192), dim3(256), 0, stream>>>(x, xT, act0a);

    dim3 blk(256);
    dim3 gcell(32, 16, 1);
    dim3 ghead(4, 16, 1);
    dim3 gexp(4, 16, 24);

    // ----- encoder -----
    for (int t = 0; t < SEQ; ++t) {
        _Float16* a0r = (t & 1) ? act0b : act0a;
        _Float16* a0w = (t & 1) ? act0a : act0b;
        _Float16* a1r = (t & 1) ? act1b : act1a;
        _Float16* a1w = (t & 1) ? act1a : act1b;
        const _Float16* xs = (t < SEQ - 1) ? (xT + (long)(t + 1) * B_SZ * 16) : nullptr;
        gemm16<1><<<gcell, blk, 0, stream>>>(a0r, 544, Wc0, 544, 0, b0i, 0, 544,
                                             c0, a0w, 544, 0, a1r, 1024, 0, xs, a0w,
                                             nullptr, 0, 0, 0, nullptr, nullptr);
        gemm16<1><<<gcell, blk, 0, stream>>>(a1r, 1024, Wc1, 1024, 0, b1i, 0, 1024,
                                             c1, a1w, 1024, 512, actDa, 544, 0, nullptr, nullptr,
                                             nullptr, 0, 0, 0, nullptr, nullptr);
    }

    // ----- decoder -----
    for (int t = 0; t < HOR; ++t) {
        _Float16* dr = (t & 1) ? actDb : actDa;
        _Float16* dw = (t & 1) ? actDa : actDb;
        gemm16<1><<<gcell, blk, 0, stream>>>(dr, 544, Wcd, 544, 0, bdi, 0, 544,
                                             c1, dw, 544, 0, nullptr, 0, 0, nullptr, nullptr,
                                             nullptr, 0, 0, 0, nullptr, nullptr);
        gemm16<0><<<ghead, blk, 0, stream>>>(dw, 544, gW1h, 512, 0, gb1, 0, 512,
                                             nullptr, nullptr, 0, 0, nullptr, 0, 0, nullptr, nullptr,
                                             t1, 256, 0, 1, nullptr, nullptr);
        gates_k<<<dim3(512), blk, 0, stream>>>(t1, gW2, gb2, gates,
                                               out + (long)32 * B_SZ, t == 0 ? 1 : 0);
        gemm16<2><<<gexp, blk, 0, stream>>>(dw, 544, W1all, 512, (long)HH * 512, b1all, 256, 512,
                                            nullptr, nullptr, 0, 0, nullptr, 0, 0, nullptr, nullptr,
                                            nullptr, 0, 0, 1, W2all, pe);
        finalize_k<<<dim3(8), blk, 0, stream>>>(pe, gates, tb2, ib2, wb2, out, dw, t);
    }
}

// Round 4
// 2512.426 us; speedup vs baseline: 8.0127x; 1.2050x over previous
//
#include <hip/hip_runtime.h>
#include <math.h>

#define B_SZ 2048
#define SEQ 64
#define FIN 16
#define H 512
#define G4 2048
#define HH 256
#define NE 8
#define HOR 8

typedef _Float16 v8h __attribute__((ext_vector_type(8)));
typedef _Float16 v4h __attribute__((ext_vector_type(4)));
typedef float v4f __attribute__((ext_vector_type(4)));

__device__ __forceinline__ void gld16(const void* g, void* l) {
    __builtin_amdgcn_global_load_lds((const __attribute__((address_space(1))) void*)g,
                                     (__attribute__((address_space(3))) void*)l, 16, 0, 0);
}
__device__ __forceinline__ v4f mfma16(v8h a, v8h b, v4f c) {
    return __builtin_amdgcn_mfma_f32_16x16x32_f16(a, b, c, 0, 0, 0);
}
__device__ __forceinline__ float rcp_(float x) { return __builtin_amdgcn_rcpf(x); }
__device__ __forceinline__ float sigf(float x) { return rcp_(1.f + __expf(-x)); }
__device__ __forceinline__ float tanhf_(float x) { return 1.f - 2.f * rcp_(1.f + __expf(2.f * x)); }

// Parameters for one fused cell GEMM: z = A @ W^T + b (gate-interleaved),
// then LSTM pointwise; h written to 1-2 fp16 buffers; optional x-copy.
struct CellP {
    const _Float16* A; int lda;
    const _Float16* W;            // dense (ldw == K)
    const float* bias; int K;
    float* cst;
    _Float16* h1p; int h1s, h1o;
    _Float16* h2p; int h2s, h2o;
    const _Float16* xsrc; _Float16* xdst;
};

// 64x64 tile, BK=32, 4 waves (2m x 2n, 32x32 each), double-buffered staging.
__device__ __forceinline__ void cell_core(const CellP P, int bx, int by)
{
    __shared__ _Float16 sAB[2][2][64 * 32];
    __shared__ float zb[64 * 68];
    const int tid = threadIdx.x;
    const int lane = tid & 63, wv = tid >> 6;
    const int m0 = by * 64, n0 = bx * 64;
    const int gr = tid >> 2, gc = (tid & 3) * 8;
    const _Float16* gA = P.A + (long)(m0 + gr) * P.lda + gc;
    const _Float16* gB = P.W + (long)(n0 + gr) * P.K + gc;
    const int wm = (wv & 1) * 32, wn = (wv >> 1) * 32;
    const int fr = lane & 15, fc = (lane >> 4) * 8, q4 = (lane >> 4) * 4;

    v4f acc[2][2];
    #pragma unroll
    for (int i = 0; i < 2; i++)
        #pragma unroll
        for (int j = 0; j < 2; j++) acc[i][j] = (v4f){0.f, 0.f, 0.f, 0.f};

    const int KT = P.K >> 5;
    {   // prefetch tile 0
        gld16(gA, sAB[0][0] + wv * 512);
        gld16(gB, sAB[0][1] + wv * 512);
        gA += 32; gB += 32;
    }
    for (int kt = 0; kt < KT; ++kt) {
        __syncthreads();
        const int cur = kt & 1;
        if (kt + 1 < KT) {
            gld16(gA, sAB[cur ^ 1][0] + wv * 512);
            gld16(gB, sAB[cur ^ 1][1] + wv * 512);
            gA += 32; gB += 32;
        }
        const _Float16* cA = sAB[cur][0];
        const _Float16* cB = sAB[cur][1];
        v8h b0 = *(const v8h*)(cB + (wn + fr) * 32 + fc);
        v8h b1 = *(const v8h*)(cB + (wn + 16 + fr) * 32 + fc);
        v8h a0 = *(const v8h*)(cA + (wm + fr) * 32 + fc);
        v8h a1 = *(const v8h*)(cA + (wm + 16 + fr) * 32 + fc);
        acc[0][0] = mfma16(a0, b0, acc[0][0]);
        acc[0][1] = mfma16(a0, b1, acc[0][1]);
        acc[1][0] = mfma16(a1, b0, acc[1][0]);
        acc[1][1] = mfma16(a1, b1, acc[1][1]);
    }
    __syncthreads();
    // z + bias into LDS (row = batch-local, col = gate-interleaved local)
    #pragma unroll
    for (int mt = 0; mt < 2; ++mt)
        #pragma unroll
        for (int nt = 0; nt < 2; ++nt) {
            int col = wn + nt * 16 + fr;
            float bv = P.bias[n0 + col];
            #pragma unroll
            for (int r = 0; r < 4; ++r)
                zb[(wm + mt * 16 + q4 + r) * 68 + col] = acc[mt][nt][r] + bv;
        }
    __syncthreads();
    // pointwise cell: thread -> (row = tid>>2, 4 units at (tid&3)*4)
    const int row = tid >> 2, ul = (tid & 3) * 4;
    const long b = m0 + row;
    const int ug = bx * 16 + ul;
    float* cp = P.cst + b * 512 + ug;
    float4 cv = *(float4*)cp;
    float cva[4] = {cv.x, cv.y, cv.z, cv.w};
    v4h hv;
    #pragma unroll
    for (int i = 0; i < 4; ++i) {
        const float* zz = &zb[row * 68 + (ul + i) * 4];
        float zi = zz[0], zf = zz[1], zg = zz[2], zo = zz[3];
        float cn = sigf(zf) * cva[i] + sigf(zi) * tanhf_(zg);
        cva[i] = cn;
        hv[i] = (_Float16)(sigf(zo) * tanhf_(cn));
    }
    *(float4*)cp = make_float4(cva[0], cva[1], cva[2], cva[3]);
    *(v4h*)(P.h1p + b * (long)P.h1s + P.h1o + ug) = hv;
    if (P.h2p) *(v4h*)(P.h2p + b * (long)P.h2s + P.h2o + ug) = hv;
    if (P.xsrc != nullptr && bx == 0) {
        *(v4h*)(P.xdst + (long)(m0 + row) * 544 + 512 + ul) =
            *(const v4h*)(P.xsrc + (long)(m0 + row) * 16 + ul);
    }
}

// zz = blockIdx.z + zbase: 0 -> P0, 1 -> P1 (two independent cell GEMMs).
__global__ __launch_bounds__(256, 4)
void cell2_k(CellP P0, CellP P1, int zbase)
{
    const int zz = blockIdx.z + zbase;
    cell_core(zz == 0 ? P0 : P1, blockIdx.x, blockIdx.y);
}

// Expert layer-1 GEMM (z<24: 24 expert slabs, fused relu+layer2 partials->pe)
// + head slab (z==24: relu -> t1).  A = dw (lda 544, K=512), W1: 25x(256x512).
__global__ __launch_bounds__(256, 4)
void expert_k(const _Float16* __restrict__ A, const _Float16* __restrict__ W1,
              const float* __restrict__ b1, const float* __restrict__ w2all,
              float* __restrict__ pe, _Float16* __restrict__ t1)
{
    __shared__ _Float16 sAB[2][2][64 * 32];
    __shared__ float red[2][64][2];
    const int tid = threadIdx.x;
    const int lane = tid & 63, wv = tid >> 6;
    const int bx = blockIdx.x, by = blockIdx.y;
    const long z = blockIdx.z;
    const int m0 = by * 64, n0 = bx * 64;
    const int gr = tid >> 2, gc = (tid & 3) * 8;
    const _Float16* gA = A + (long)(m0 + gr) * 544 + gc;
    const _Float16* gB = W1 + z * 256 * 512 + (long)(n0 + gr) * 512 + gc;
    const int wm = (wv & 1) * 32, wn = (wv >> 1) * 32;
    const int fr = lane & 15, fc = (lane >> 4) * 8, q4 = (lane >> 4) * 4;

    v4f acc[2][2];
    #pragma unroll
    for (int i = 0; i < 2; i++)
        #pragma unroll
        for (int j = 0; j < 2; j++) acc[i][j] = (v4f){0.f, 0.f, 0.f, 0.f};

    {
        gld16(gA, sAB[0][0] + wv * 512);
        gld16(gB, sAB[0][1] + wv * 512);
        gA += 32; gB += 32;
    }
    for (int kt = 0; kt < 16; ++kt) {
        __syncthreads();
        const int cur = kt & 1;
        if (kt + 1 < 16) {
            gld16(gA, sAB[cur ^ 1][0] + wv * 512);
            gld16(gB, sAB[cur ^ 1][1] + wv * 512);
            gA += 32; gB += 32;
        }
        const _Float16* cA = sAB[cur][0];
        const _Float16* cB = sAB[cur][1];
        v8h b0 = *(const v8h*)(cB + (wn + fr) * 32 + fc);
        v8h b1v = *(const v8h*)(cB + (wn + 16 + fr) * 32 + fc);
        v8h a0 = *(const v8h*)(cA + (wm + fr) * 32 + fc);
        v8h a1 = *(const v8h*)(cA + (wm + 16 + fr) * 32 + fc);
        acc[0][0] = mfma16(a0, b0, acc[0][0]);
        acc[0][1] = mfma16(a0, b1v, acc[0][1]);
        acc[1][0] = mfma16(a1, b0, acc[1][0]);
        acc[1][1] = mfma16(a1, b1v, acc[1][1]);
    }

    if (z == 24) {   // head slab -> t1 (fp16, row-major 2048x256)
        #pragma unroll
        for (int mt = 0; mt < 2; ++mt)
            #pragma unroll
            for (int nt = 0; nt < 2; ++nt) {
                int col = wn + nt * 16 + fr;
                float bv = b1[24 * 256 + n0 + col];
                #pragma unroll
                for (int r = 0; r < 4; ++r) {
                    float v = fmaxf(acc[mt][nt][r] + bv, 0.f);
                    t1[(long)(m0 + wm + mt * 16 + q4 + r) * 256 + n0 + col] = (_Float16)v;
                }
            }
        return;
    }
    // expert slab: relu, dot with layer-2 weights, reduce cols -> pe
    float w0[2], w1[2], bv[2];
    #pragma unroll
    for (int nt = 0; nt < 2; ++nt) {
        int colg = n0 + wn + nt * 16 + fr;
        w0[nt] = w2all[(z * 2 + 0) * 256 + colg];
        w1[nt] = w2all[(z * 2 + 1) * 256 + colg];
        bv[nt] = b1[z * 256 + colg];
    }
    float p0[2][4], p1[2][4];
    #pragma unroll
    for (int mt = 0; mt < 2; ++mt)
        #pragma unroll
        for (int r = 0; r < 4; ++r) { p0[mt][r] = 0.f; p1[mt][r] = 0.f; }
    #pragma unroll
    for (int mt = 0; mt < 2; ++mt)
        #pragma unroll
        for (int nt = 0; nt < 2; ++nt)
            #pragma unroll
            for (int r = 0; r < 4; ++r) {
                float v = fmaxf(acc[mt][nt][r] + bv[nt], 0.f);
                p0[mt][r] = fmaf(v, w0[nt], p0[mt][r]);
                p1[mt][r] = fmaf(v, w1[nt], p1[mt][r]);
            }
    #pragma unroll
    for (int off = 1; off < 16; off <<= 1)
        #pragma unroll
        for (int mt = 0; mt < 2; ++mt)
            #pragma unroll
            for (int r = 0; r < 4; ++r) {
                p0[mt][r] += __shfl_xor(p0[mt][r], off, 64);
                p1[mt][r] += __shfl_xor(p1[mt][r], off, 64);
            }
    if ((lane & 15) == 0) {
        #pragma unroll
        for (int mt = 0; mt < 2; ++mt)
            #pragma unroll
            for (int r = 0; r < 4; ++r) {
                int row = wm + mt * 16 + q4 + r;
                red[wv >> 1][row][0] = p0[mt][r];
                red[wv >> 1][row][1] = p1[mt][r];
            }
    }
    __syncthreads();
    if (tid < 64) {
        #pragma unroll
        for (int o = 0; o < 2; ++o) {
            float v = red[0][tid][o] + red[1][tid][o];
            pe[(((long)bx * 24 + z) * 2 + o) * 2048 + m0 + tid] = v;
        }
    }
}

// Gate head softmax + running gates_avg. 4 rows/block.
__global__ __launch_bounds__(256)
void gates_k(const _Float16* __restrict__ t1, const float* __restrict__ gW2,
             const float* __restrict__ gb2, float* __restrict__ gates,
             float* __restrict__ gavg, int first)
{
    const int w = threadIdx.x >> 6, lane = threadIdx.x & 63;
    const int b = blockIdx.x * 4 + w;
    v4h xv = *(const v4h*)(t1 + (long)b * HH + lane * 4);
    float x0 = xv[0], x1 = xv[1], x2 = xv[2], x3 = xv[3];
    float acc[NE];
    #pragma unroll
    for (int e = 0; e < NE; e++) {
        const float* w2 = gW2 + e * HH + lane * 4;
        acc[e] = x0 * w2[0] + x1 * w2[1] + x2 * w2[2] + x3 * w2[3];
    }
    #pragma unroll
    for (int off = 1; off < 64; off <<= 1)
        #pragma unroll
        for (int e = 0; e < NE; e++) acc[e] += __shfl_xor(acc[e], off, 64);
    if (lane == 0) {
        float mx = -1e30f;
        #pragma unroll
        for (int e = 0; e < NE; e++) { acc[e] += gb2[e]; mx = fmaxf(mx, acc[e]); }
        float s = 0.f;
        #pragma unroll
        for (int e = 0; e < NE; e++) { acc[e] = __expf(acc[e] - mx); s += acc[e]; }
        float inv = 1.f / s;
        #pragma unroll
        for (int e = 0; e < NE; e++) {
            float ge = acc[e] * inv;
            gates[(long)b * NE + e] = ge;
            float prev = first ? 0.f : gavg[(long)b * NE + e];
            gavg[(long)b * NE + e] = prev + ge * (1.f / HOR);
        }
    }
}

// Gate-weighted combine of expert partials; outputs + dec_in.
__global__ __launch_bounds__(256)
void finalize_k(const float* __restrict__ pe, const float* __restrict__ gates,
                const float* __restrict__ tb2, const float* __restrict__ ib2,
                const float* __restrict__ wb2,
                float* __restrict__ out, _Float16* __restrict__ dw, int step)
{
    const int b = blockIdx.x * 256 + threadIdx.x;
    float t0 = 0.f, t1v = 0.f, iv = 0.f, wvv = 0.f;
    #pragma unroll
    for (int e = 0; e < NE; e++) {
        float g = gates[(long)b * NE + e];
        float s00 = 0.f, s01 = 0.f, s10 = 0.f, s20 = 0.f;
        #pragma unroll
        for (int nb = 0; nb < 4; ++nb) {
            long base0 = (((long)nb * 24 + e) * 2) * 2048 + b;
            s00 += pe[base0];
            s01 += pe[base0 + 2048];
            s10 += pe[(((long)nb * 24 + 8 + e) * 2) * 2048 + b];
            s20 += pe[(((long)nb * 24 + 16 + e) * 2) * 2048 + b];
        }
        t0  += g * (s00 + tb2[e * 2 + 0]);
        t1v += g * (s01 + tb2[e * 2 + 1]);
        iv  += g * (s10 + ib2[e]);
        wvv += g * (s20 + wb2[e]);
    }
    out[(long)b * 16 + step] = t0;
    out[(long)b * 16 + 8 + step] = t1v;
    out[(long)16 * B_SZ + (long)b * 8 + step] = iv;
    out[(long)24 * B_SZ + (long)b * 8 + step] = wvv;
    _Float16* d = dw + (long)b * 544 + 512;
    d[0] = (_Float16)t0; d[1] = (_Float16)t1v; d[2] = (_Float16)iv; d[3] = (_Float16)wvv;
}

// Gate-interleaved fp16 cell weight + bias (zeros beyond K1+K2 pad to KOUT).
__global__ __launch_bounds__(256)
void prep_cellw(const float* __restrict__ s1, int K1, const float* __restrict__ s2, int K2,
                _Float16* __restrict__ dst, int KOUT,
                const float* __restrict__ bs, float* __restrict__ bd)
{
    int np = blockIdx.x;
    int u = np >> 2, g = np & 3;
    int srow = g * 512 + u;
    const float* r1 = s1 + (long)srow * K1;
    const float* r2 = s2 + (long)srow * K2;
    _Float16* d = dst + (long)np * KOUT;
    for (int k = threadIdx.x; k < KOUT; k += 256) {
        float v = 0.f;
        if (k < K1) v = r1[k];
        else if (k < K1 + K2) v = r2[k - K1];
        d[k] = (_Float16)v;
    }
    if (threadIdx.x == 0) bd[np] = bs[srow];
}

__global__ __launch_bounds__(256)
void cvt16(const float* __restrict__ s, _Float16* __restrict__ d, long n)
{
    long i = (long)blockIdx.x * 256 + threadIdx.x;
    if (i < n) d[i] = (_Float16)s[i];
}

__global__ __launch_bounds__(256)
void cat4(const float* __restrict__ a, const float* __restrict__ b,
          const float* __restrict__ c, const float* __restrict__ g,
          float* __restrict__ d)
{
    int i = blockIdx.x * 256 + threadIdx.x;   // < 6400
    float v;
    if (i < 2048) v = a[i];
    else if (i < 4096) v = b[i - 2048];
    else if (i < 6144) v = c[i - 4096];
    else v = g[i - 6144];
    d[i] = v;
}

__global__ __launch_bounds__(256)
void prep_w2(const float* __restrict__ tW2, const float* __restrict__ iW2,
             const float* __restrict__ wW2, float* __restrict__ W2all)
{
    int i = blockIdx.x * 256 + threadIdx.x;   // < 24*2*256
    int j = i & 255, o = (i >> 8) & 1, zz = i >> 9;
    int br = zz >> 3, e = zz & 7;
    float v = 0.f;
    if (br == 0) v = tW2[(e * 2 + o) * 256 + j];
    else if (o == 0) v = (br == 1 ? iW2 : wW2)[e * 256 + j];
    W2all[i] = v;
}

__global__ __launch_bounds__(256)
void prep_x(const float* __restrict__ x, _Float16* __restrict__ xT, _Float16* __restrict__ act00)
{
    long i = (long)blockIdx.x * 256 + threadIdx.x;
    int f = (int)(i & 15);
    long bs = i >> 4;
    int s = (int)(bs & 63);
    long b = bs >> 6;
    float v = x[i];
    xT[((long)s * B_SZ + b) * 16 + f] = (_Float16)v;
    if (s == 0) act00[b * 544 + 512 + f] = (_Float16)v;
}

extern "C" void kernel_launch(void* const* d_in, const int* in_sizes, int n_in,
                              void* d_out, int out_size, void* d_ws, size_t ws_size,
                              hipStream_t stream)
{
    const float* x    = (const float*)d_in[0];
    const float* Wih0 = (const float*)d_in[1];
    const float* Whh0 = (const float*)d_in[2];
    const float* b0   = (const float*)d_in[3];
    const float* Wih1 = (const float*)d_in[4];
    const float* Whh1 = (const float*)d_in[5];
    const float* b1   = (const float*)d_in[6];
    const float* dWih = (const float*)d_in[7];
    const float* dWhh = (const float*)d_in[8];
    const float* db   = (const float*)d_in[9];
    const float* gW1  = (const float*)d_in[10];
    const float* gb1  = (const float*)d_in[11];
    const float* gW2  = (const float*)d_in[12];
    const float* gb2  = (const float*)d_in[13];
    const float* tW1  = (const float*)d_in[14];
    const float* tb1  = (const float*)d_in[15];
    const float* tW2  = (const float*)d_in[16];
    const float* tb2  = (const float*)d_in[17];
    const float* iW1  = (const float*)d_in[18];
    const float* ib1  = (const float*)d_in[19];
    const float* iW2  = (const float*)d_in[20];
    const float* ib2  = (const float*)d_in[21];
    const float* wW1  = (const float*)d_in[22];
    const float* wb1  = (const float*)d_in[23];
    const float* wW2  = (const float*)d_in[24];
    const float* wb2  = (const float*)d_in[25];
    float* out = (float*)d_out;

    char* p = (char*)d_ws;
    auto alloc = [&](size_t bytes) { char* r = p; p += (bytes + 255) & ~255ULL; return r; };
    _Float16* xT    = (_Float16*)alloc((size_t)SEQ * B_SZ * 16 * 2);
    _Float16* act0a = (_Float16*)alloc((size_t)B_SZ * 544 * 2);
    _Float16* act0b = (_Float16*)alloc((size_t)B_SZ * 544 * 2);
    _Float16* act1a = (_Float16*)alloc((size_t)B_SZ * 1024 * 2);
    _Float16* act1b = (_Float16*)alloc((size_t)B_SZ * 1024 * 2);
    _Float16* actDa = (_Float16*)alloc((size_t)B_SZ * 544 * 2);
    _Float16* actDb = (_Float16*)alloc((size_t)B_SZ * 544 * 2);
    float*    c0    = (float*)alloc((size_t)B_SZ * 512 * 4);
    float*    c1    = (float*)alloc((size_t)B_SZ * 512 * 4);
    _Float16* Wc0   = (_Float16*)alloc((size_t)G4 * 544 * 2);
    _Float16* Wc1   = (_Float16*)alloc((size_t)G4 * 1024 * 2);
    _Float16* Wcd   = (_Float16*)alloc((size_t)G4 * 544 * 2);
    float*    b0i   = (float*)alloc((size_t)G4 * 4);
    float*    b1i   = (float*)alloc((size_t)G4 * 4);
    float*    bdi   = (float*)alloc((size_t)G4 * 4);
    _Float16* W1all = (_Float16*)alloc((size_t)25 * HH * 512 * 2);
    float*    b1all = (float*)alloc((size_t)25 * HH * 4);
    float*    W2all = (float*)alloc((size_t)24 * 2 * 256 * 4);
    _Float16* t1    = (_Float16*)alloc((size_t)B_SZ * HH * 2);
    float*    gates = (float*)alloc((size_t)B_SZ * NE * 4);
    float*    pe    = (float*)alloc((size_t)4 * 24 * 2 * 2048 * 4);

    hipMemsetAsync(act0a, 0, (size_t)B_SZ * 544 * 2, stream);
    hipMemsetAsync(act0b, 0, (size_t)B_SZ * 544 * 2, stream);
    hipMemsetAsync(act1a, 0, (size_t)B_SZ * 1024 * 2, stream);
    hipMemsetAsync(act1b, 0, (size_t)B_SZ * 1024 * 2, stream);
    hipMemsetAsync(actDa, 0, (size_t)B_SZ * 544 * 2, stream);
    hipMemsetAsync(actDb, 0, (size_t)B_SZ * 544 * 2, stream);
    hipMemsetAsync(c0, 0, (size_t)B_SZ * 512 * 4, stream);
    hipMemsetAsync(c1, 0, (size_t)B_SZ * 512 * 4, stream);

    prep_cellw<<<dim3(G4), dim3(256), 0, stream>>>(Whh0, 512, Wih0, 16, Wc0, 544, b0, b0i);
    prep_cellw<<<dim3(G4), dim3(256), 0, stream>>>(Wih1, 512, Whh1, 512, Wc1, 1024, b1, b1i);
    prep_cellw<<<dim3(G4), dim3(256), 0, stream>>>(dWhh, 512, dWih, 4, Wcd, 544, db, bdi);
    cvt16<<<dim3(4096), dim3(256), 0, stream>>>(tW1, W1all, (long)NE * HH * 512);
    cvt16<<<dim3(4096), dim3(256), 0, stream>>>(iW1, W1all + (long)NE * HH * 512, (long)NE * HH * 512);
    cvt16<<<dim3(4096), dim3(256), 0, stream>>>(wW1, W1all + (long)16 * HH * 512, (long)NE * HH * 512);
    cvt16<<<dim3(512), dim3(256), 0, stream>>>(gW1, W1all + (long)24 * HH * 512, (long)HH * 512);
    cat4<<<dim3(25), dim3(256), 0, stream>>>(tb1, ib1, wb1, gb1, b1all);
    prep_w2<<<dim3(48), dim3(256), 0, stream>>>(tW2, iW2, wW2, W2all);
    prep_x<<<dim3(8192), dim3(256), 0, stream>>>(x, xT, act0a);

    _Float16* act0[2] = {act0a, act0b};
    _Float16* act1[2] = {act1a, act1b};

    // ----- encoder: 65 merged launches; launch s runs L0 step s and L1 step s-1 -----
    for (int s = 0; s <= SEQ; ++s) {
        const bool do0 = (s < SEQ), do1 = (s >= 1);
        CellP P0 = {}, P1 = {};
        if (do0) {
            P0.A = act0[s & 1]; P0.lda = 544; P0.W = Wc0; P0.bias = b0i; P0.K = 544;
            P0.cst = c0;
            P0.h1p = act0[(s + 1) & 1]; P0.h1s = 544; P0.h1o = 0;
            P0.h2p = act1[s & 1]; P0.h2s = 1024; P0.h2o = 0;
            P0.xsrc = (s < SEQ - 1) ? (xT + (long)(s + 1) * B_SZ * 16) : nullptr;
            P0.xdst = act0[(s + 1) & 1];
        }
        if (do1) {
            P1.A = act1[(s + 1) & 1]; P1.lda = 1024; P1.W = Wc1; P1.bias = b1i; P1.K = 1024;
            P1.cst = c1;
            P1.h1p = act1[s & 1]; P1.h1s = 1024; P1.h1o = 512;
            P1.h2p = (s == SEQ) ? actDa : nullptr; P1.h2s = 544; P1.h2o = 0;
            P1.xsrc = nullptr; P1.xdst = nullptr;
        }
        const int nz = (do0 && do1) ? 2 : 1;
        const int zbase = do0 ? 0 : 1;
        cell2_k<<<dim3(32, 32, nz), dim3(256), 0, stream>>>(P0, P1, zbase);
    }

    // ----- decoder: 8 steps x 4 launches -----
    for (int t = 0; t < HOR; ++t) {
        _Float16* dr = (t & 1) ? actDb : actDa;
        _Float16* dw = (t & 1) ? actDa : actDb;
        CellP PD = {};
        PD.A = dr; PD.lda = 544; PD.W = Wcd; PD.bias = bdi; PD.K = 544;
        PD.cst = c1;
        PD.h1p = dw; PD.h1s = 544; PD.h1o = 0;
        PD.h2p = nullptr; PD.xsrc = nullptr; PD.xdst = nullptr;
        cell2_k<<<dim3(32, 32, 1), dim3(256), 0, stream>>>(PD, PD, 0);
        expert_k<<<dim3(4, 32, 25), dim3(256), 0, stream>>>(dw, W1all, b1all, W2all, pe, t1);
        gates_k<<<dim3(512), dim3(256), 0, stream>>>(t1, gW2, gb2, gates,
                                                     out + (long)32 * B_SZ, t == 0 ? 1 : 0);
        finalize_k<<<dim3(8), dim3(256), 0, stream>>>(pe, gates, tb2, ib2, wb2, out, dw, t);
    }
}

// Round 5
// 2072.776 us; speedup vs baseline: 9.7123x; 1.2121x over previous
//
#include <hip/hip_runtime.h>
#include <math.h>

#define B_SZ 2048
#define SEQ 64
#define H 512
#define G4 2048
#define HH 256
#define NE 8
#define HOR 8

typedef _Float16 v8h __attribute__((ext_vector_type(8)));
typedef _Float16 v4h __attribute__((ext_vector_type(4)));
typedef float v4f __attribute__((ext_vector_type(4)));

__device__ __forceinline__ void gld16(const void* g, void* l) {
    __builtin_amdgcn_global_load_lds((const __attribute__((address_space(1))) void*)g,
                                     (__attribute__((address_space(3))) void*)l, 16, 0, 0);
}
__device__ __forceinline__ v4f mfma16(v8h a, v8h b, v4f c) {
    return __builtin_amdgcn_mfma_f32_16x16x32_f16(a, b, c, 0, 0, 0);
}
__device__ __forceinline__ float rcp_(float x) { return __builtin_amdgcn_rcpf(x); }
__device__ __forceinline__ float sigf(float x) { return rcp_(1.f + __expf(-x)); }
__device__ __forceinline__ float tanhf_(float x) { return 1.f - 2.f * rcp_(1.f + __expf(2.f * x)); }

// Fragment-chunk layout: operand stored as [chunk16rows][ktile][lane64][8]
// where chunk[l*8+j] = M[c*16 + (l&15)][kt*32 + (l>>4)*8 + j].  1KB chunks:
// gld16 stages one chunk per wave; frag read = ds_read_b128 @ base+lane*16.

struct CellP {
    const _Float16* Af; int KTA;       // A frag buffer, its total k-tiles
    const _Float16* Bf;                // weight frag buffer (dense, KT tiles)
    const float* bias; int KT;         // K-loop tiles
    float* cst;
    _Float16* h1p; int h1kt, h1o;      // dest buffers (frag layout)
    _Float16* h2p; int h2kt, h2o;
    const _Float16* xsrc; _Float16* xdst;   // x-copy into xdst (17-tile buf, ktile 16)
};

// Block 128x128, 4 waves (2x2), wave tile 64x64, BK=32, dbuf staging.
__global__ __launch_bounds__(256, 4)
void cell2_k(CellP P0, CellP P1, int zbase)
{
    __shared__ __align__(16) char smem[34816];
    const CellP& P = (blockIdx.z + zbase == 0) ? P0 : P1;
    _Float16* st = (_Float16*)smem;
    float* zb = (float*)smem;                 // 128 x 68 (union after K-loop)
    const int tid = threadIdx.x, lane = tid & 63, wv = tid >> 6;
    const int bx = blockIdx.x, by = blockIdx.y;
    const int KT = P.KT;

    const _Float16* pA0 = P.Af + ((long)(by * 8 + 2 * wv) * P.KTA) * 512 + lane * 8;
    const _Float16* pA1 = P.Af + ((long)(by * 8 + 2 * wv + 1) * P.KTA) * 512 + lane * 8;
    const _Float16* pB0 = P.Bf + ((long)(bx * 8 + 2 * wv) * KT) * 512 + lane * 8;
    const _Float16* pB1 = P.Bf + ((long)(bx * 8 + 2 * wv + 1) * KT) * 512 + lane * 8;
    const int oA0 = 2 * wv * 512, oA1 = oA0 + 512;
    const int oB0 = 4096 + 2 * wv * 512, oB1 = oB0 + 512;
    const int wm = (wv & 1) * 64, wn = (wv >> 1) * 64;
    const int fr = lane & 15, q4 = (lane >> 4) * 4;

    v4f acc[4][4];
    #pragma unroll
    for (int i = 0; i < 4; i++)
        #pragma unroll
        for (int j = 0; j < 4; j++) acc[i][j] = (v4f){0.f, 0.f, 0.f, 0.f};

    gld16(pA0, st + oA0); gld16(pA1, st + oA1);
    gld16(pB0, st + oB0); gld16(pB1, st + oB1);
    pA0 += 512; pA1 += 512; pB0 += 512; pB1 += 512;

    for (int kt = 0; kt < KT; ++kt) {
        __syncthreads();
        const int cur = kt & 1;
        if (kt + 1 < KT) {
            _Float16* nb = st + (cur ^ 1) * 8192;
            gld16(pA0, nb + oA0); gld16(pA1, nb + oA1);
            gld16(pB0, nb + oB0); gld16(pB1, nb + oB1);
            pA0 += 512; pA1 += 512; pB0 += 512; pB1 += 512;
        }
        const _Float16* base = st + cur * 8192;
        v8h bf[4];
        #pragma unroll
        for (int nt = 0; nt < 4; ++nt)
            bf[nt] = *(const v8h*)(base + 4096 + ((wv >> 1) * 4 + nt) * 512 + lane * 8);
        #pragma unroll
        for (int mt = 0; mt < 4; ++mt) {
            v8h a = *(const v8h*)(base + ((wv & 1) * 4 + mt) * 512 + lane * 8);
            #pragma unroll
            for (int nt = 0; nt < 4; ++nt)
                acc[mt][nt] = mfma16(a, bf[nt], acc[mt][nt]);
        }
    }

    // ---- cell epilogue, two 64-col halves (zb unions with staging) ----
    #pragma unroll
    for (int half = 0; half < 2; ++half) {
        __syncthreads();
        if ((wv >> 1) == half) {
            #pragma unroll
            for (int mt = 0; mt < 4; ++mt)
                #pragma unroll
                for (int nt = 0; nt < 4; ++nt) {
                    int col = nt * 16 + fr;                      // 0..63 within half
                    float bv = P.bias[bx * 128 + half * 64 + col];
                    #pragma unroll
                    for (int r = 0; r < 4; ++r)
                        zb[(wm + mt * 16 + q4 + r) * 68 + col] = acc[mt][nt][r] + bv;
                }
        }
        __syncthreads();
        const int row = tid >> 1, u8 = (tid & 1) * 8;
        const long b = by * 128 + row;
        const int ug = bx * 32 + half * 16 + u8;
        float* cp = P.cst + b * 512 + ug;
        float4 cl0 = *(float4*)cp, cl1 = *(float4*)(cp + 4);
        float cv[8] = {cl0.x, cl0.y, cl0.z, cl0.w, cl1.x, cl1.y, cl1.z, cl1.w};
        v8h hv;
        #pragma unroll
        for (int i = 0; i < 8; ++i) {
            const float* zz = &zb[row * 68 + (u8 + i) * 4];
            float cn = sigf(zz[1]) * cv[i] + sigf(zz[0]) * tanhf_(zz[2]);
            cv[i] = cn;
            hv[i] = (_Float16)(sigf(zz[3]) * tanhf_(cn));
        }
        *(float4*)cp = make_float4(cv[0], cv[1], cv[2], cv[3]);
        *(float4*)(cp + 4) = make_float4(cv[4], cv[5], cv[6], cv[7]);
        {
            int kk = P.h1o + ug;
            long a = ((b >> 4) * (long)P.h1kt + (kk >> 5)) * 512 + (((kk & 31) >> 3) * 16 + (b & 15)) * 8;
            *(v8h*)(P.h1p + a) = hv;
        }
        if (P.h2p) {
            int kk = P.h2o + ug;
            long a = ((b >> 4) * (long)P.h2kt + (kk >> 5)) * 512 + (((kk & 31) >> 3) * 16 + (b & 15)) * 8;
            *(v8h*)(P.h2p + a) = hv;
        }
        if (half == 0 && P.xsrc != nullptr && bx == 0) {
            int mc = tid >> 5, l = tid & 31;
            v8h xv = *(const v8h*)(P.xsrc + ((long)(by * 8 + mc) * 32 + l) * 8);
            *(v8h*)(P.xdst + (((long)(by * 8 + mc)) * 17 + 16) * 512 + l * 8) = xv;
        }
    }
}

// Expert layer-1 (+fused relu & layer-2 partial) for z<24; head slab z==24 -> t1.
__global__ __launch_bounds__(256, 4)
void expert_k(const _Float16* __restrict__ Af, const _Float16* __restrict__ W1f,
              const float* __restrict__ b1, const float* __restrict__ w2all,
              float* __restrict__ pe, _Float16* __restrict__ t1)
{
    __shared__ __align__(16) char smem[32768];
    _Float16* st = (_Float16*)smem;
    float* red = (float*)smem;
    const int tid = threadIdx.x, lane = tid & 63, wv = tid >> 6;
    const int bx = blockIdx.x, by = blockIdx.y;
    const long z = blockIdx.z;

    const _Float16* pA0 = Af + ((long)(by * 8 + 2 * wv) * 17) * 512 + lane * 8;
    const _Float16* pA1 = Af + ((long)(by * 8 + 2 * wv + 1) * 17) * 512 + lane * 8;
    const _Float16* pB0 = W1f + ((z * 16 + bx * 8 + 2 * wv) * 16) * 512 + lane * 8;
    const _Float16* pB1 = W1f + ((z * 16 + bx * 8 + 2 * wv + 1) * 16) * 512 + lane * 8;
    const int oA0 = 2 * wv * 512, oA1 = oA0 + 512;
    const int oB0 = 4096 + 2 * wv * 512, oB1 = oB0 + 512;
    const int wm = (wv & 1) * 64, wn = (wv >> 1) * 64;
    const int fr = lane & 15, q4 = (lane >> 4) * 4;

    v4f acc[4][4];
    #pragma unroll
    for (int i = 0; i < 4; i++)
        #pragma unroll
        for (int j = 0; j < 4; j++) acc[i][j] = (v4f){0.f, 0.f, 0.f, 0.f};

    gld16(pA0, st + oA0); gld16(pA1, st + oA1);
    gld16(pB0, st + oB0); gld16(pB1, st + oB1);
    pA0 += 512; pA1 += 512; pB0 += 512; pB1 += 512;

    for (int kt = 0; kt < 16; ++kt) {
        __syncthreads();
        const int cur = kt & 1;
        if (kt + 1 < 16) {
            _Float16* nb = st + (cur ^ 1) * 8192;
            gld16(pA0, nb + oA0); gld16(pA1, nb + oA1);
            gld16(pB0, nb + oB0); gld16(pB1, nb + oB1);
            pA0 += 512; pA1 += 512; pB0 += 512; pB1 += 512;
        }
        const _Float16* base = st + cur * 8192;
        v8h bf[4];
        #pragma unroll
        for (int nt = 0; nt < 4; ++nt)
            bf[nt] = *(const v8h*)(base + 4096 + ((wv >> 1) * 4 + nt) * 512 + lane * 8);
        #pragma unroll
        for (int mt = 0; mt < 4; ++mt) {
            v8h a = *(const v8h*)(base + ((wv & 1) * 4 + mt) * 512 + lane * 8);
            #pragma unroll
            for (int nt = 0; nt < 4; ++nt)
                acc[mt][nt] = mfma16(a, bf[nt], acc[mt][nt]);
        }
    }
    __syncthreads();

    if (z == 24) {     // head -> t1 (2048 x 256 fp16 row-major)
        #pragma unroll
        for (int mt = 0; mt < 4; ++mt)
            #pragma unroll
            for (int nt = 0; nt < 4; ++nt) {
                int col = bx * 128 + wn + nt * 16 + fr;
                float bv = b1[24 * 256 + col];
                #pragma unroll
                for (int r = 0; r < 4; ++r) {
                    float v = fmaxf(acc[mt][nt][r] + bv, 0.f);
                    t1[(long)(by * 128 + wm + mt * 16 + q4 + r) * 256 + col] = (_Float16)v;
                }
            }
        return;
    }
    float w0[4], w1[4], bv[4];
    #pragma unroll
    for (int nt = 0; nt < 4; ++nt) {
        int col = bx * 128 + wn + nt * 16 + fr;
        w0[nt] = w2all[(z * 2 + 0) * 256 + col];
        w1[nt] = w2all[(z * 2 + 1) * 256 + col];
        bv[nt] = b1[z * 256 + col];
    }
    float p0[4][4], p1[4][4];
    #pragma unroll
    for (int mt = 0; mt < 4; ++mt)
        #pragma unroll
        for (int r = 0; r < 4; ++r) { p0[mt][r] = 0.f; p1[mt][r] = 0.f; }
    #pragma unroll
    for (int mt = 0; mt < 4; ++mt)
        #pragma unroll
        for (int nt = 0; nt < 4; ++nt)
            #pragma unroll
            for (int r = 0; r < 4; ++r) {
                float v = fmaxf(acc[mt][nt][r] + bv[nt], 0.f);
                p0[mt][r] = fmaf(v, w0[nt], p0[mt][r]);
                p1[mt][r] = fmaf(v, w1[nt], p1[mt][r]);
            }
    #pragma unroll
    for (int off = 1; off < 16; off <<= 1)
        #pragma unroll
        for (int mt = 0; mt < 4; ++mt)
            #pragma unroll
            for (int r = 0; r < 4; ++r) {
                p0[mt][r] += __shfl_xor(p0[mt][r], off, 64);
                p1[mt][r] += __shfl_xor(p1[mt][r], off, 64);
            }
    if ((lane & 15) == 0) {
        #pragma unroll
        for (int mt = 0; mt < 4; ++mt)
            #pragma unroll
            for (int r = 0; r < 4; ++r) {
                int row = wm + mt * 16 + q4 + r;
                red[(((wv >> 1) * 128) + row) * 2 + 0] = p0[mt][r];
                red[(((wv >> 1) * 128) + row) * 2 + 1] = p1[mt][r];
            }
    }
    __syncthreads();
    if (tid < 128) {
        #pragma unroll
        for (int o = 0; o < 2; ++o) {
            float v = red[tid * 2 + o] + red[(128 + tid) * 2 + o];
            pe[(((long)bx * 24 + z) * 2 + o) * 2048 + by * 128 + tid] = v;
        }
    }
}

// Gates (softmax of t1 @ gW2^T + gb2) + gates_avg + gated expert combine + outputs.
__global__ __launch_bounds__(256)
void fin_k(const _Float16* __restrict__ t1, const float* __restrict__ gW2,
           const float* __restrict__ gb2, const float* __restrict__ pe,
           const float* __restrict__ tb2, const float* __restrict__ ib2,
           const float* __restrict__ wb2,
           float* __restrict__ out, _Float16* __restrict__ dw, int step)
{
    const long b = blockIdx.x * 256 + threadIdx.x;
    float acc[NE];
    #pragma unroll
    for (int e = 0; e < NE; e++) acc[e] = gb2[e];
    for (int j = 0; j < 256; j += 8) {
        v8h tv = *(const v8h*)(t1 + b * 256 + j);
        #pragma unroll
        for (int k = 0; k < 8; ++k) {
            float xv = (float)tv[k];
            #pragma unroll
            for (int e = 0; e < NE; e++) acc[e] = fmaf(xv, gW2[e * 256 + j + k], acc[e]);
        }
    }
    float mx = -1e30f;
    #pragma unroll
    for (int e = 0; e < NE; e++) mx = fmaxf(mx, acc[e]);
    float s = 0.f;
    #pragma unroll
    for (int e = 0; e < NE; e++) { acc[e] = __expf(acc[e] - mx); s += acc[e]; }
    float inv = 1.f / s;
    float t0 = 0.f, t1v = 0.f, iv = 0.f, wvv = 0.f;
    #pragma unroll
    for (int e = 0; e < NE; e++) {
        float g = acc[e] * inv;
        float prev = step == 0 ? 0.f : out[32 * (long)B_SZ + b * NE + e];
        out[32 * (long)B_SZ + b * NE + e] = prev + g * (1.f / HOR);
        float s00 = pe[((0 * 24 + e) * 2 + 0) * 2048 + b] + pe[((1 * 24 + e) * 2 + 0) * 2048 + b];
        float s01 = pe[((0 * 24 + e) * 2 + 1) * 2048 + b] + pe[((1 * 24 + e) * 2 + 1) * 2048 + b];
        float s10 = pe[((0 * 24 + 8 + e) * 2 + 0) * 2048 + b] + pe[((1 * 24 + 8 + e) * 2 + 0) * 2048 + b];
        float s20 = pe[((0 * 24 + 16 + e) * 2 + 0) * 2048 + b] + pe[((1 * 24 + 16 + e) * 2 + 0) * 2048 + b];
        t0  += g * (s00 + tb2[e * 2 + 0]);
        t1v += g * (s01 + tb2[e * 2 + 1]);
        iv  += g * (s10 + ib2[e]);
        wvv += g * (s20 + wb2[e]);
    }
    out[b * 16 + step] = t0;
    out[b * 16 + 8 + step] = t1v;
    out[16 * (long)B_SZ + b * 8 + step] = iv;
    out[24 * (long)B_SZ + b * 8 + step] = wvv;
    v4h dv = {(_Float16)t0, (_Float16)t1v, (_Float16)iv, (_Float16)wvv};
    *(v4h*)(dw + ((b >> 4) * 17 + 16) * 512 + (b & 15) * 8) = dv;
}

// Gate-interleaved cell weights -> fragment-chunk layout (+ interleaved bias).
__global__ __launch_bounds__(64)
void prep_wfrag(const float* __restrict__ s1, int K1, const float* __restrict__ s2, int K2,
                _Float16* __restrict__ dst, int KT,
                const float* __restrict__ bs, float* __restrict__ bd)
{
    const int nc = blockIdx.x, kt = blockIdx.y, l = threadIdx.x;
    const int nprime = nc * 16 + (l & 15);
    const int u = nprime >> 2, g = nprime & 3, srow = g * 512 + u;
    v8h v;
    #pragma unroll
    for (int j = 0; j < 8; ++j) {
        int k = kt * 32 + (l >> 4) * 8 + j;
        float val = 0.f;
        if (k < K1) val = s1[(long)srow * K1 + k];
        else if (k < K1 + K2) val = s2[(long)srow * K2 + k - K1];
        v[j] = (_Float16)val;
    }
    *(v8h*)(dst + ((long)nc * KT + kt) * 512 + l * 8) = v;
    if (kt == 0 && l < 16) bd[nc * 16 + l] = bs[((nc * 16 + l) & 3) * 512 + ((nc * 16 + l) >> 2)];
}

// Expert/head layer-1 weights -> fragment-chunk layout, 25 slabs.
__global__ __launch_bounds__(64)
void prep_w1frag(const float* __restrict__ tW1, const float* __restrict__ iW1,
                 const float* __restrict__ wW1, const float* __restrict__ gW1,
                 _Float16* __restrict__ dst)
{
    const int nc = blockIdx.x & 15, kt = blockIdx.x >> 4, z = blockIdx.y, l = threadIdx.x;
    const float* src;
    if (z < 8) src = tW1 + (long)z * 256 * 512;
    else if (z < 16) src = iW1 + (long)(z - 8) * 256 * 512;
    else if (z < 24) src = wW1 + (long)(z - 16) * 256 * 512;
    else src = gW1;
    const int row = nc * 16 + (l & 15);
    v8h v;
    #pragma unroll
    for (int j = 0; j < 8; ++j)
        v[j] = (_Float16)src[(long)row * 512 + kt * 32 + (l >> 4) * 8 + j];
    *(v8h*)(dst + (((long)z * 16 + nc) * 16 + kt) * 512 + l * 8) = v;
}

__global__ __launch_bounds__(256)
void cat4(const float* __restrict__ a, const float* __restrict__ b,
          const float* __restrict__ c, const float* __restrict__ g,
          float* __restrict__ d)
{
    int i = blockIdx.x * 256 + threadIdx.x;   // < 6400
    float v;
    if (i < 2048) v = a[i];
    else if (i < 4096) v = b[i - 2048];
    else if (i < 6144) v = c[i - 4096];
    else v = g[i - 6144];
    d[i] = v;
}

__global__ __launch_bounds__(256)
void prep_w2(const float* __restrict__ tW2, const float* __restrict__ iW2,
             const float* __restrict__ wW2, float* __restrict__ W2all)
{
    int i = blockIdx.x * 256 + threadIdx.x;   // < 24*2*256
    int j = i & 255, o = (i >> 8) & 1, zz = i >> 9;
    int br = zz >> 3, e = zz & 7;
    float v = 0.f;
    if (br == 0) v = tW2[(e * 2 + o) * 256 + j];
    else if (o == 0) v = (br == 1 ? iW2 : wW2)[e * 256 + j];
    W2all[i] = v;
}

// x (B,S,16) -> per-step fragment chunks xTf[s][mc][l(32)][8]; seed act0a ktile16.
__global__ __launch_bounds__(256)
void prep_xf(const float* __restrict__ x, _Float16* __restrict__ xTf,
             _Float16* __restrict__ act0a)
{
    const int t = blockIdx.x * 256 + threadIdx.x;   // < 64*128*32
    const int l = t & 31, mc = (t >> 5) & 127, s = t >> 12;
    const long b = mc * 16 + (l & 15);
    const float* src = x + (b * 64 + s) * 16 + (l >> 4) * 8;
    v8h v;
    #pragma unroll
    for (int j = 0; j < 8; ++j) v[j] = (_Float16)src[j];
    *(v8h*)(xTf + (((long)s * 128 + mc) * 32 + l) * 8) = v;
    if (s == 0) *(v8h*)(act0a + ((long)mc * 17 + 16) * 512 + l * 8) = v;
}

extern "C" void kernel_launch(void* const* d_in, const int* in_sizes, int n_in,
                              void* d_out, int out_size, void* d_ws, size_t ws_size,
                              hipStream_t stream)
{
    const float* x    = (const float*)d_in[0];
    const float* Wih0 = (const float*)d_in[1];
    const float* Whh0 = (const float*)d_in[2];
    const float* b0   = (const float*)d_in[3];
    const float* Wih1 = (const float*)d_in[4];
    const float* Whh1 = (const float*)d_in[5];
    const float* b1   = (const float*)d_in[6];
    const float* dWih = (const float*)d_in[7];
    const float* dWhh = (const float*)d_in[8];
    const float* db   = (const float*)d_in[9];
    const float* gW1  = (const float*)d_in[10];
    const float* gb1  = (const float*)d_in[11];
    const float* gW2  = (const float*)d_in[12];
    const float* gb2  = (const float*)d_in[13];
    const float* tW1  = (const float*)d_in[14];
    const float* tb1  = (const float*)d_in[15];
    const float* tW2  = (const float*)d_in[16];
    const float* tb2  = (const float*)d_in[17];
    const float* iW1  = (const float*)d_in[18];
    const float* ib1  = (const float*)d_in[19];
    const float* iW2  = (const float*)d_in[20];
    const float* ib2  = (const float*)d_in[21];
    const float* wW1  = (const float*)d_in[22];
    const float* wb1  = (const float*)d_in[23];
    const float* wW2  = (const float*)d_in[24];
    const float* wb2  = (const float*)d_in[25];
    float* out = (float*)d_out;

    char* p = (char*)d_ws;
    auto alloc = [&](size_t bytes) { char* r = p; p += (bytes + 255) & ~255ULL; return r; };
    _Float16* xTf   = (_Float16*)alloc((size_t)SEQ * 128 * 32 * 8 * 2);
    _Float16* act0a = (_Float16*)alloc((size_t)128 * 17 * 512 * 2);
    _Float16* act0b = (_Float16*)alloc((size_t)128 * 17 * 512 * 2);
    _Float16* act1a = (_Float16*)alloc((size_t)128 * 32 * 512 * 2);
    _Float16* act1b = (_Float16*)alloc((size_t)128 * 32 * 512 * 2);
    _Float16* actDa = (_Float16*)alloc((size_t)128 * 17 * 512 * 2);
    _Float16* actDb = (_Float16*)alloc((size_t)128 * 17 * 512 * 2);
    float*    c0    = (float*)alloc((size_t)B_SZ * 512 * 4);
    float*    c1    = (float*)alloc((size_t)B_SZ * 512 * 4);
    _Float16* Wc0   = (_Float16*)alloc((size_t)128 * 17 * 512 * 2);
    _Float16* Wc1   = (_Float16*)alloc((size_t)128 * 32 * 512 * 2);
    _Float16* Wcd   = (_Float16*)alloc((size_t)128 * 17 * 512 * 2);
    float*    b0i   = (float*)alloc((size_t)G4 * 4);
    float*    b1i   = (float*)alloc((size_t)G4 * 4);
    float*    bdi   = (float*)alloc((size_t)G4 * 4);
    _Float16* W1all = (_Float16*)alloc((size_t)25 * 16 * 16 * 512 * 2);
    float*    b1all = (float*)alloc((size_t)25 * HH * 4);
    float*    W2all = (float*)alloc((size_t)24 * 2 * 256 * 4);
    _Float16* t1    = (_Float16*)alloc((size_t)B_SZ * HH * 2);
    float*    pe    = (float*)alloc((size_t)2 * 24 * 2 * 2048 * 4);

    hipMemsetAsync(act0a, 0, (size_t)128 * 17 * 512 * 2, stream);
    hipMemsetAsync(act0b, 0, (size_t)128 * 17 * 512 * 2, stream);
    hipMemsetAsync(act1a, 0, (size_t)128 * 32 * 512 * 2, stream);
    hipMemsetAsync(act1b, 0, (size_t)128 * 32 * 512 * 2, stream);
    hipMemsetAsync(actDa, 0, (size_t)128 * 17 * 512 * 2, stream);
    hipMemsetAsync(actDb, 0, (size_t)128 * 17 * 512 * 2, stream);
    hipMemsetAsync(c0, 0, (size_t)B_SZ * 512 * 4, stream);
    hipMemsetAsync(c1, 0, (size_t)B_SZ * 512 * 4, stream);

    prep_wfrag<<<dim3(128, 17), dim3(64), 0, stream>>>(Whh0, 512, Wih0, 16, Wc0, 17, b0, b0i);
    prep_wfrag<<<dim3(128, 32), dim3(64), 0, stream>>>(Wih1, 512, Whh1, 512, Wc1, 32, b1, b1i);
    prep_wfrag<<<dim3(128, 17), dim3(64), 0, stream>>>(dWhh, 512, dWih, 4, Wcd, 17, db, bdi);
    prep_w1frag<<<dim3(256, 25), dim3(64), 0, stream>>>(tW1, iW1, wW1, gW1, W1all);
    cat4<<<dim3(25), dim3(256), 0, stream>>>(tb1, ib1, wb1, gb1, b1all);
    prep_w2<<<dim3(48), dim3(256), 0, stream>>>(tW2, iW2, wW2, W2all);
    prep_xf<<<dim3(1024), dim3(256), 0, stream>>>(x, xTf, act0a);

    _Float16* act0[2] = {act0a, act0b};
    _Float16* act1[2] = {act1a, act1b};

    // ----- encoder: merged launch s runs L0_s and L1_{s-1} -----
    for (int s = 0; s <= SEQ; ++s) {
        const bool do0 = (s < SEQ), do1 = (s >= 1);
        CellP P0 = {}, P1 = {};
        if (do0) {
            P0.Af = act0[s & 1]; P0.KTA = 17;
            P0.Bf = Wc0; P0.bias = b0i; P0.KT = 17;
            P0.cst = c0;
            P0.h1p = act0[(s + 1) & 1]; P0.h1kt = 17; P0.h1o = 0;
            P0.h2p = act1[s & 1]; P0.h2kt = 32; P0.h2o = 0;
            P0.xsrc = (s < SEQ - 1) ? (xTf + ((long)(s + 1) * 128 * 32) * 8) : nullptr;
            P0.xdst = act0[(s + 1) & 1];
        }
        if (do1) {
            P1.Af = act1[(s + 1) & 1]; P1.KTA = 32;
            P1.Bf = Wc1; P1.bias = b1i; P1.KT = 32;
            P1.cst = c1;
            P1.h1p = act1[s & 1]; P1.h1kt = 32; P1.h1o = 512;
            P1.h2p = (s == SEQ) ? actDa : nullptr; P1.h2kt = 17; P1.h2o = 0;
            P1.xsrc = nullptr; P1.xdst = nullptr;
        }
        const int nz = (do0 && do1) ? 2 : 1;
        const int zbase = do0 ? 0 : 1;
        cell2_k<<<dim3(16, 16, nz), dim3(256), 0, stream>>>(P0, P1, zbase);
    }

    // ----- decoder: 8 steps x 3 launches -----
    for (int t = 0; t < HOR; ++t) {
        _Float16* dr = (t & 1) ? actDb : actDa;
        _Float16* dw = (t & 1) ? actDa : actDb;
        CellP PD = {};
        PD.Af = dr; PD.KTA = 17;
        PD.Bf = Wcd; PD.bias = bdi; PD.KT = 17;
        PD.cst = c1;
        PD.h1p = dw; PD.h1kt = 17; PD.h1o = 0;
        PD.h2p = nullptr; PD.xsrc = nullptr; PD.xdst = nullptr;
        cell2_k<<<dim3(16, 16, 1), dim3(256), 0, stream>>>(PD, PD, 0);
        expert_k<<<dim3(2, 16, 25), dim3(256), 0, stream>>>(dw, W1all, b1all, W2all, pe, t1);
        fin_k<<<dim3(8), dim3(256), 0, stream>>>(t1, gW2, gb2, pe, tb2, ib2, wb2, out, dw, t);
    }
}

// Round 8
// 1973.549 us; speedup vs baseline: 10.2006x; 1.0503x over previous
//
#include <hip/hip_runtime.h>
#include <math.h>

#define B_SZ 2048
#define SEQ 64
#define H 512
#define G4 2048
#define HH 256
#define NE 8
#define HOR 8

typedef _Float16 v8h __attribute__((ext_vector_type(8)));
typedef _Float16 v4h __attribute__((ext_vector_type(4)));
typedef float v4f __attribute__((ext_vector_type(4)));

__device__ __forceinline__ void gld16(const void* g, void* l) {
    __builtin_amdgcn_global_load_lds((const __attribute__((address_space(1))) void*)g,
                                     (__attribute__((address_space(3))) void*)l, 16, 0, 0);
}
__device__ __forceinline__ v4f mfma16(v8h a, v8h b, v4f c) {
    return __builtin_amdgcn_mfma_f32_16x16x32_f16(a, b, c, 0, 0, 0);
}
__device__ __forceinline__ float rcp_(float x) { return __builtin_amdgcn_rcpf(x); }
__device__ __forceinline__ float sigf(float x) { return rcp_(1.f + __expf(-x)); }
__device__ __forceinline__ float tanhf_(float x) { return 1.f - 2.f * rcp_(1.f + __expf(2.f * x)); }

// Fragment-chunk layout: operand stored as [chunk16rows][ktile][lane64][8];
// chunk[l*8+j] = M[c*16 + (l&15)][kt*32 + (l>>4)*8 + j].
// Cell GEMM K padded to a multiple of 64 (18 ktiles for K=544+pad) so the
// BK=64 double-tile loop has no tail; pad tiles are zeros (bitwise-neutral).

struct CellP {
    const _Float16* Af; int KTA;       // A frag buffer, its total k-tiles (even)
    const _Float16* Bf;                // weight frag buffer (dense, KT tiles)
    const float* bias; int KT;         // K-loop tiles (even)
    float* cst;
    _Float16* h1p; int h1kt, h1o;      // dest buffers (frag layout)
    _Float16* h2p; int h2kt, h2o;
    const _Float16* xsrc; _Float16* xdst;   // x-copy into xdst (18-tile buf, ktile 16)
};

// Block 128x128, 4 waves (2x2), wave tile 64x64, BK=64 (2 ktiles/iter),
// double-buffered staging (32 KB per buffer, 64 KB LDS -> 2 blocks/CU,
// which the merged grid (512 blocks) is limited to anyway).
__global__ __launch_bounds__(256, 2)
void cell2_k(CellP P0, CellP P1, int zbase)
{
    __shared__ __align__(16) char smem[65536];
    const CellP& P = (blockIdx.z + zbase == 0) ? P0 : P1;
    _Float16* st = (_Float16*)smem;
    float* zb = (float*)smem;                 // 128 x 68 fp32 (union after K-loop)
    const int tid = threadIdx.x, lane = tid & 63, wv = tid >> 6;
    const int bx = blockIdx.x, by = blockIdx.y;
    const int NIT = P.KT >> 1;                // 64-k iterations

    const _Float16* pA0 = P.Af + ((long)(by * 8 + 2 * wv) * P.KTA) * 512 + lane * 8;
    const _Float16* pA1 = P.Af + ((long)(by * 8 + 2 * wv + 1) * P.KTA) * 512 + lane * 8;
    const _Float16* pB0 = P.Bf + ((long)(bx * 8 + 2 * wv) * P.KT) * 512 + lane * 8;
    const _Float16* pB1 = P.Bf + ((long)(bx * 8 + 2 * wv + 1) * P.KT) * 512 + lane * 8;
    const int oA = 4 * wv * 512;              // LDS chunk offsets (wave-uniform)
    const int oB = 8192 + 4 * wv * 512;
    const int wm = (wv & 1) * 64;
    const int fr = lane & 15, q4 = (lane >> 4) * 4;

    v4f acc[4][4];
    #pragma unroll
    for (int i = 0; i < 4; i++)
        #pragma unroll
        for (int j = 0; j < 4; j++) acc[i][j] = (v4f){0.f, 0.f, 0.f, 0.f};

    auto stage = [&](int buf, int it) {
        _Float16* d = st + buf * 16384;
        const long ko = (long)it * 1024;      // 2 ktiles = 1024 elements
        gld16(pA0 + ko,       d + oA);
        gld16(pA0 + ko + 512, d + oA + 512);
        gld16(pA1 + ko,       d + oA + 1024);
        gld16(pA1 + ko + 512, d + oA + 1536);
        gld16(pB0 + ko,       d + oB);
        gld16(pB0 + ko + 512, d + oB + 512);
        gld16(pB1 + ko,       d + oB + 1024);
        gld16(pB1 + ko + 512, d + oB + 1536);
    };

    stage(0, 0);
    for (int it = 0; it < NIT; ++it) {
        __syncthreads();                       // drains vmcnt -> staged tiles visible
        if (it + 1 < NIT) stage((it & 1) ^ 1, it + 1);
        const _Float16* base = st + (it & 1) * 16384;
        #pragma unroll
        for (int p = 0; p < 2; ++p) {          // sub-ktile within the 64-k tile
            v8h bf[4];
            #pragma unroll
            for (int nt = 0; nt < 4; ++nt)
                bf[nt] = *(const v8h*)(base + 8192 + (((wv >> 1) * 4 + nt) * 2 + p) * 512 + lane * 8);
            #pragma unroll
            for (int mt = 0; mt < 4; ++mt) {
                v8h a = *(const v8h*)(base + (((wv & 1) * 4 + mt) * 2 + p) * 512 + lane * 8);
                #pragma unroll
                for (int nt = 0; nt < 4; ++nt)
                    acc[mt][nt] = mfma16(a, bf[nt], acc[mt][nt]);
            }
        }
    }

    // ---- cell epilogue, two 64-col halves (zb unions with staging) ----
    #pragma unroll
    for (int half = 0; half < 2; ++half) {
        __syncthreads();
        if ((wv >> 1) == half) {
            #pragma unroll
            for (int mt = 0; mt < 4; ++mt)
                #pragma unroll
                for (int nt = 0; nt < 4; ++nt) {
                    int col = nt * 16 + fr;                      // 0..63 within half
                    float bv = P.bias[bx * 128 + half * 64 + col];
                    #pragma unroll
                    for (int r = 0; r < 4; ++r)
                        zb[(wm + mt * 16 + q4 + r) * 68 + col] = acc[mt][nt][r] + bv;
                }
        }
        __syncthreads();
        const int row = tid >> 1, u8 = (tid & 1) * 8;
        const long b = by * 128 + row;
        const int ug = bx * 32 + half * 16 + u8;
        float* cp = P.cst + b * 512 + ug;
        float4 cl0 = *(float4*)cp, cl1 = *(float4*)(cp + 4);
        float cv[8] = {cl0.x, cl0.y, cl0.z, cl0.w, cl1.x, cl1.y, cl1.z, cl1.w};
        v8h hv;
        #pragma unroll
        for (int i = 0; i < 8; ++i) {
            const float* zz = &zb[row * 68 + (u8 + i) * 4];
            float cn = sigf(zz[1]) * cv[i] + sigf(zz[0]) * tanhf_(zz[2]);
            cv[i] = cn;
            hv[i] = (_Float16)(sigf(zz[3]) * tanhf_(cn));
        }
        *(float4*)cp = make_float4(cv[0], cv[1], cv[2], cv[3]);
        *(float4*)(cp + 4) = make_float4(cv[4], cv[5], cv[6], cv[7]);
        {
            int kk = P.h1o + ug;
            long a = ((b >> 4) * (long)P.h1kt + (kk >> 5)) * 512 + (((kk & 31) >> 3) * 16 + (b & 15)) * 8;
            *(v8h*)(P.h1p + a) = hv;
        }
        if (P.h2p) {
            int kk = P.h2o + ug;
            long a = ((b >> 4) * (long)P.h2kt + (kk >> 5)) * 512 + (((kk & 31) >> 3) * 16 + (b & 15)) * 8;
            *(v8h*)(P.h2p + a) = hv;
        }
        if (half == 0 && P.xsrc != nullptr && bx == 0) {
            int mc = tid >> 5, l = tid & 31;
            v8h xv = *(const v8h*)(P.xsrc + ((long)(by * 8 + mc) * 32 + l) * 8);
            *(v8h*)(P.xdst + (((long)(by * 8 + mc)) * 18 + 16) * 512 + l * 8) = xv;
        }
    }
}

// Expert layer-1 (+fused relu & layer-2 partial) for z<24; head slab z==24 -> t1.
// (BK=32 kept here: 800-block grid benefits from 4 blocks/CU at 32 KB LDS.)
__global__ __launch_bounds__(256, 4)
void expert_k(const _Float16* __restrict__ Af, const _Float16* __restrict__ W1f,
              const float* __restrict__ b1, const float* __restrict__ w2all,
              float* __restrict__ pe, _Float16* __restrict__ t1)
{
    __shared__ __align__(16) char smem[32768];
    _Float16* st = (_Float16*)smem;
    float* red = (float*)smem;
    const int tid = threadIdx.x, lane = tid & 63, wv = tid >> 6;
    const int bx = blockIdx.x, by = blockIdx.y;
    const long z = blockIdx.z;

    const _Float16* pA0 = Af + ((long)(by * 8 + 2 * wv) * 18) * 512 + lane * 8;
    const _Float16* pA1 = Af + ((long)(by * 8 + 2 * wv + 1) * 18) * 512 + lane * 8;
    const _Float16* pB0 = W1f + ((z * 16 + bx * 8 + 2 * wv) * 16) * 512 + lane * 8;
    const _Float16* pB1 = W1f + ((z * 16 + bx * 8 + 2 * wv + 1) * 16) * 512 + lane * 8;
    const int oA0 = 2 * wv * 512, oA1 = oA0 + 512;
    const int oB0 = 4096 + 2 * wv * 512, oB1 = oB0 + 512;
    const int wm = (wv & 1) * 64, wn = (wv >> 1) * 64;
    const int fr = lane & 15, q4 = (lane >> 4) * 4;

    v4f acc[4][4];
    #pragma unroll
    for (int i = 0; i < 4; i++)
        #pragma unroll
        for (int j = 0; j < 4; j++) acc[i][j] = (v4f){0.f, 0.f, 0.f, 0.f};

    gld16(pA0, st + oA0); gld16(pA1, st + oA1);
    gld16(pB0, st + oB0); gld16(pB1, st + oB1);
    pA0 += 512; pA1 += 512; pB0 += 512; pB1 += 512;

    for (int kt = 0; kt < 16; ++kt) {
        __syncthreads();
        const int cur = kt & 1;
        if (kt + 1 < 16) {
            _Float16* nb = st + (cur ^ 1) * 8192;
            gld16(pA0, nb + oA0); gld16(pA1, nb + oA1);
            gld16(pB0, nb + oB0); gld16(pB1, nb + oB1);
            pA0 += 512; pA1 += 512; pB0 += 512; pB1 += 512;
        }
        const _Float16* base = st + cur * 8192;
        v8h bf[4];
        #pragma unroll
        for (int nt = 0; nt < 4; ++nt)
            bf[nt] = *(const v8h*)(base + 4096 + ((wv >> 1) * 4 + nt) * 512 + lane * 8);
        #pragma unroll
        for (int mt = 0; mt < 4; ++mt) {
            v8h a = *(const v8h*)(base + ((wv & 1) * 4 + mt) * 512 + lane * 8);
            #pragma unroll
            for (int nt = 0; nt < 4; ++nt)
                acc[mt][nt] = mfma16(a, bf[nt], acc[mt][nt]);
        }
    }
    __syncthreads();

    if (z == 24) {     // head -> t1 (2048 x 256 fp16 row-major)
        #pragma unroll
        for (int mt = 0; mt < 4; ++mt)
            #pragma unroll
            for (int nt = 0; nt < 4; ++nt) {
                int col = bx * 128 + wn + nt * 16 + fr;
                float bv = b1[24 * 256 + col];
                #pragma unroll
                for (int r = 0; r < 4; ++r) {
                    float v = fmaxf(acc[mt][nt][r] + bv, 0.f);
                    t1[(long)(by * 128 + wm + mt * 16 + q4 + r) * 256 + col] = (_Float16)v;
                }
            }
        return;
    }
    float w0[4], w1[4], bv[4];
    #pragma unroll
    for (int nt = 0; nt < 4; ++nt) {
        int col = bx * 128 + wn + nt * 16 + fr;
        w0[nt] = w2all[(z * 2 + 0) * 256 + col];
        w1[nt] = w2all[(z * 2 + 1) * 256 + col];
        bv[nt] = b1[z * 256 + col];
    }
    float p0[4][4], p1[4][4];
    #pragma unroll
    for (int mt = 0; mt < 4; ++mt)
        #pragma unroll
        for (int r = 0; r < 4; ++r) { p0[mt][r] = 0.f; p1[mt][r] = 0.f; }
    #pragma unroll
    for (int mt = 0; mt < 4; ++mt)
        #pragma unroll
        for (int nt = 0; nt < 4; ++nt)
            #pragma unroll
            for (int r = 0; r < 4; ++r) {
                float v = fmaxf(acc[mt][nt][r] + bv[nt], 0.f);
                p0[mt][r] = fmaf(v, w0[nt], p0[mt][r]);
                p1[mt][r] = fmaf(v, w1[nt], p1[mt][r]);
            }
    #pragma unroll
    for (int off = 1; off < 16; off <<= 1)
        #pragma unroll
        for (int mt = 0; mt < 4; ++mt)
            #pragma unroll
            for (int r = 0; r < 4; ++r) {
                p0[mt][r] += __shfl_xor(p0[mt][r], off, 64);
                p1[mt][r] += __shfl_xor(p1[mt][r], off, 64);
            }
    if ((lane & 15) == 0) {
        #pragma unroll
        for (int mt = 0; mt < 4; ++mt)
            #pragma unroll
            for (int r = 0; r < 4; ++r) {
                int rw = wm + mt * 16 + q4 + r;
                red[(((wv >> 1) * 128) + rw) * 2 + 0] = p0[mt][r];
                red[(((wv >> 1) * 128) + rw) * 2 + 1] = p1[mt][r];
            }
    }
    __syncthreads();
    if (tid < 128) {
        #pragma unroll
        for (int o = 0; o < 2; ++o) {
            float v = red[tid * 2 + o] + red[(128 + tid) * 2 + o];
            pe[(((long)bx * 24 + z) * 2 + o) * 2048 + by * 128 + tid] = v;
        }
    }
}

// Gates softmax + gates_avg + gated expert combine + outputs + dec_in.
__global__ __launch_bounds__(256)
void fin_k(const _Float16* __restrict__ t1, const float* __restrict__ gW2,
           const float* __restrict__ gb2, const float* __restrict__ pe,
           const float* __restrict__ tb2, const float* __restrict__ ib2,
           const float* __restrict__ wb2,
           float* __restrict__ out, _Float16* __restrict__ dw, int step)
{
    const long b = blockIdx.x * 256 + threadIdx.x;
    float acc[NE];
    #pragma unroll
    for (int e = 0; e < NE; e++) acc[e] = gb2[e];
    for (int j = 0; j < 256; j += 8) {
        v8h tv = *(const v8h*)(t1 + b * 256 + j);
        #pragma unroll
        for (int k = 0; k < 8; ++k) {
            float xv = (float)tv[k];
            #pragma unroll
            for (int e = 0; e < NE; e++) acc[e] = fmaf(xv, gW2[e * 256 + j + k], acc[e]);
        }
    }
    float mx = -1e30f;
    #pragma unroll
    for (int e = 0; e < NE; e++) mx = fmaxf(mx, acc[e]);
    float s = 0.f;
    #pragma unroll
    for (int e = 0; e < NE; e++) { acc[e] = __expf(acc[e] - mx); s += acc[e]; }
    float inv = 1.f / s;
    float t0 = 0.f, t1v = 0.f, iv = 0.f, wvv = 0.f;
    #pragma unroll
    for (int e = 0; e < NE; e++) {
        float g = acc[e] * inv;
        float prev = step == 0 ? 0.f : out[32 * (long)B_SZ + b * NE + e];
        out[32 * (long)B_SZ + b * NE + e] = prev + g * (1.f / HOR);
        float s00 = pe[((0 * 24 + e) * 2 + 0) * 2048 + b] + pe[((1 * 24 + e) * 2 + 0) * 2048 + b];
        float s01 = pe[((0 * 24 + e) * 2 + 1) * 2048 + b] + pe[((1 * 24 + e) * 2 + 1) * 2048 + b];
        float s10 = pe[((0 * 24 + 8 + e) * 2 + 0) * 2048 + b] + pe[((1 * 24 + 8 + e) * 2 + 0) * 2048 + b];
        float s20 = pe[((0 * 24 + 16 + e) * 2 + 0) * 2048 + b] + pe[((1 * 24 + 16 + e) * 2 + 0) * 2048 + b];
        t0  += g * (s00 + tb2[e * 2 + 0]);
        t1v += g * (s01 + tb2[e * 2 + 1]);
        iv  += g * (s10 + ib2[e]);
        wvv += g * (s20 + wb2[e]);
    }
    out[b * 16 + step] = t0;
    out[b * 16 + 8 + step] = t1v;
    out[16 * (long)B_SZ + b * 8 + step] = iv;
    out[24 * (long)B_SZ + b * 8 + step] = wvv;
    v4h dv = {(_Float16)t0, (_Float16)t1v, (_Float16)iv, (_Float16)wvv};
    *(v4h*)(dw + ((b >> 4) * 18 + 16) * 512 + (b & 15) * 8) = dv;
}

// Gate-interleaved cell weights -> fragment-chunk layout (+ interleaved bias).
__global__ __launch_bounds__(64)
void prep_wfrag(const float* __restrict__ s1, int K1, const float* __restrict__ s2, int K2,
                _Float16* __restrict__ dst, int KT,
                const float* __restrict__ bs, float* __restrict__ bd)
{
    const int nc = blockIdx.x, kt = blockIdx.y, l = threadIdx.x;
    const int nprime = nc * 16 + (l & 15);
    const int u = nprime >> 2, g = nprime & 3, srow = g * 512 + u;
    v8h v;
    #pragma unroll
    for (int j = 0; j < 8; ++j) {
        int k = kt * 32 + (l >> 4) * 8 + j;
        float val = 0.f;
        if (k < K1) val = s1[(long)srow * K1 + k];
        else if (k < K1 + K2) val = s2[(long)srow * K2 + k - K1];
        v[j] = (_Float16)val;
    }
    *(v8h*)(dst + ((long)nc * KT + kt) * 512 + l * 8) = v;
    if (kt == 0 && l < 16) bd[nc * 16 + l] = bs[((nc * 16 + l) & 3) * 512 + ((nc * 16 + l) >> 2)];
}

__global__ __launch_bounds__(64)
void prep_w1frag(const float* __restrict__ tW1, const float* __restrict__ iW1,
                 const float* __restrict__ wW1, const float* __restrict__ gW1,
                 _Float16* __restrict__ dst)
{
    const int nc = blockIdx.x & 15, kt = blockIdx.x >> 4, z = blockIdx.y, l = threadIdx.x;
    const float* src;
    if (z < 8) src = tW1 + (long)z * 256 * 512;
    else if (z < 16) src = iW1 + (long)(z - 8) * 256 * 512;
    else if (z < 24) src = wW1 + (long)(z - 16) * 256 * 512;
    else src = gW1;
    const int row = nc * 16 + (l & 15);
    v8h v;
    #pragma unroll
    for (int j = 0; j < 8; ++j)
        v[j] = (_Float16)src[(long)row * 512 + kt * 32 + (l >> 4) * 8 + j];
    *(v8h*)(dst + (((long)z * 16 + nc) * 16 + kt) * 512 + l * 8) = v;
}

__global__ __launch_bounds__(256)
void cat4(const float* __restrict__ a, const float* __restrict__ b,
          const float* __restrict__ c, const float* __restrict__ g,
          float* __restrict__ d)
{
    int i = blockIdx.x * 256 + threadIdx.x;   // < 6400
    float v;
    if (i < 2048) v = a[i];
    else if (i < 4096) v = b[i - 2048];
    else if (i < 6144) v = c[i - 4096];
    else v = g[i - 6144];
    d[i] = v;
}

__global__ __launch_bounds__(256)
void prep_w2(const float* __restrict__ tW2, const float* __restrict__ iW2,
             const float* __restrict__ wW2, float* __restrict__ W2all)
{
    int i = blockIdx.x * 256 + threadIdx.x;   // < 24*2*256
    int j = i & 255, o = (i >> 8) & 1, zz = i >> 9;
    int br = zz >> 3, e = zz & 7;
    float v = 0.f;
    if (br == 0) v = tW2[(e * 2 + o) * 256 + j];
    else if (o == 0) v = (br == 1 ? iW2 : wW2)[e * 256 + j];
    W2all[i] = v;
}

// x (B,S,16) -> per-step fragment chunks xTf[s][mc][l(32)][8]; seed act0a ktile16.
__global__ __launch_bounds__(256)
void prep_xf(const float* __restrict__ x, _Float16* __restrict__ xTf,
             _Float16* __restrict__ act0a)
{
    const int t = blockIdx.x * 256 + threadIdx.x;   // < 64*128*32
    const int l = t & 31, mc = (t >> 5) & 127, s = t >> 12;
    const long b = mc * 16 + (l & 15);
    const float* src = x + (b * 64 + s) * 16 + (l >> 4) * 8;
    v8h v;
    #pragma unroll
    for (int j = 0; j < 8; ++j) v[j] = (_Float16)src[j];
    *(v8h*)(xTf + (((long)s * 128 + mc) * 32 + l) * 8) = v;
    if (s == 0) *(v8h*)(act0a + ((long)mc * 18 + 16) * 512 + l * 8) = v;
}

extern "C" void kernel_launch(void* const* d_in, const int* in_sizes, int n_in,
                              void* d_out, int out_size, void* d_ws, size_t ws_size,
                              hipStream_t stream)
{
    const float* x    = (const float*)d_in[0];
    const float* Wih0 = (const float*)d_in[1];
    const float* Whh0 = (const float*)d_in[2];
    const float* b0   = (const float*)d_in[3];
    const float* Wih1 = (const float*)d_in[4];
    const float* Whh1 = (const float*)d_in[5];
    const float* b1   = (const float*)d_in[6];
    const float* dWih = (const float*)d_in[7];
    const float* dWhh = (const float*)d_in[8];
    const float* db   = (const float*)d_in[9];
    const float* gW1  = (const float*)d_in[10];
    const float* gb1  = (const float*)d_in[11];
    const float* gW2  = (const float*)d_in[12];
    const float* gb2  = (const float*)d_in[13];
    const float* tW1  = (const float*)d_in[14];
    const float* tb1  = (const float*)d_in[15];
    const float* tW2  = (const float*)d_in[16];
    const float* tb2  = (const float*)d_in[17];
    const float* iW1  = (const float*)d_in[18];
    const float* ib1  = (const float*)d_in[19];
    const float* iW2  = (const float*)d_in[20];
    const float* ib2  = (const float*)d_in[21];
    const float* wW1  = (const float*)d_in[22];
    const float* wb1  = (const float*)d_in[23];
    const float* wW2  = (const float*)d_in[24];
    const float* wb2  = (const float*)d_in[25];
    float* out = (float*)d_out;

    char* p = (char*)d_ws;
    auto alloc = [&](size_t bytes) { char* r = p; p += (bytes + 255) & ~255ULL; return r; };
    _Float16* xTf   = (_Float16*)alloc((size_t)SEQ * 128 * 32 * 8 * 2);
    _Float16* act0a = (_Float16*)alloc((size_t)128 * 18 * 512 * 2);
    _Float16* act0b = (_Float16*)alloc((size_t)128 * 18 * 512 * 2);
    _Float16* act1a = (_Float16*)alloc((size_t)128 * 32 * 512 * 2);
    _Float16* act1b = (_Float16*)alloc((size_t)128 * 32 * 512 * 2);
    _Float16* actDa = (_Float16*)alloc((size_t)128 * 18 * 512 * 2);
    _Float16* actDb = (_Float16*)alloc((size_t)128 * 18 * 512 * 2);
    float*    c0    = (float*)alloc((size_t)B_SZ * 512 * 4);
    float*    c1    = (float*)alloc((size_t)B_SZ * 512 * 4);
    _Float16* Wc0   = (_Float16*)alloc((size_t)128 * 18 * 512 * 2);
    _Float16* Wc1   = (_Float16*)alloc((size_t)128 * 32 * 512 * 2);
    _Float16* Wcd   = (_Float16*)alloc((size_t)128 * 18 * 512 * 2);
    float*    b0i   = (float*)alloc((size_t)G4 * 4);
    float*    b1i   = (float*)alloc((size_t)G4 * 4);
    float*    bdi   = (float*)alloc((size_t)G4 * 4);
    _Float16* W1all = (_Float16*)alloc((size_t)25 * 16 * 16 * 512 * 2);
    float*    b1all = (float*)alloc((size_t)25 * HH * 4);
    float*    W2all = (float*)alloc((size_t)24 * 2 * 256 * 4);
    _Float16* t1    = (_Float16*)alloc((size_t)B_SZ * HH * 2);
    float*    pe    = (float*)alloc((size_t)2 * 24 * 2 * 2048 * 4);

    hipMemsetAsync(act0a, 0, (size_t)128 * 18 * 512 * 2, stream);
    hipMemsetAsync(act0b, 0, (size_t)128 * 18 * 512 * 2, stream);
    hipMemsetAsync(act1a, 0, (size_t)128 * 32 * 512 * 2, stream);
    hipMemsetAsync(act1b, 0, (size_t)128 * 32 * 512 * 2, stream);
    hipMemsetAsync(actDa, 0, (size_t)128 * 18 * 512 * 2, stream);
    hipMemsetAsync(actDb, 0, (size_t)128 * 18 * 512 * 2, stream);
    hipMemsetAsync(c0, 0, (size_t)B_SZ * 512 * 4, stream);
    hipMemsetAsync(c1, 0, (size_t)B_SZ * 512 * 4, stream);

    prep_wfrag<<<dim3(128, 18), dim3(64), 0, stream>>>(Whh0, 512, Wih0, 16, Wc0, 18, b0, b0i);
    prep_wfrag<<<dim3(128, 32), dim3(64), 0, stream>>>(Wih1, 512, Whh1, 512, Wc1, 32, b1, b1i);
    prep_wfrag<<<dim3(128, 18), dim3(64), 0, stream>>>(dWhh, 512, dWih, 4, Wcd, 18, db, bdi);
    prep_w1frag<<<dim3(256, 25), dim3(64), 0, stream>>>(tW1, iW1, wW1, gW1, W1all);
    cat4<<<dim3(25), dim3(256), 0, stream>>>(tb1, ib1, wb1, gb1, b1all);
    prep_w2<<<dim3(48), dim3(256), 0, stream>>>(tW2, iW2, wW2, W2all);
    prep_xf<<<dim3(1024), dim3(256), 0, stream>>>(x, xTf, act0a);

    _Float16* act0[2] = {act0a, act0b};
    _Float16* act1[2] = {act1a, act1b};

    // ----- encoder: merged launch s runs L0_s and L1_{s-1} -----
    for (int s = 0; s <= SEQ; ++s) {
        const bool do0 = (s < SEQ), do1 = (s >= 1);
        CellP P0 = {}, P1 = {};
        if (do0) {
            P0.Af = act0[s & 1]; P0.KTA = 18;
            P0.Bf = Wc0; P0.bias = b0i; P0.KT = 18;
            P0.cst = c0;
            P0.h1p = act0[(s + 1) & 1]; P0.h1kt = 18; P0.h1o = 0;
            P0.h2p = act1[s & 1]; P0.h2kt = 32; P0.h2o = 0;
            P0.xsrc = (s < SEQ - 1) ? (xTf + ((long)(s + 1) * 128 * 32) * 8) : nullptr;
            P0.xdst = act0[(s + 1) & 1];
        }
        if (do1) {
            P1.Af = act1[(s + 1) & 1]; P1.KTA = 32;
            P1.Bf = Wc1; P1.bias = b1i; P1.KT = 32;
            P1.cst = c1;
            P1.h1p = act1[s & 1]; P1.h1kt = 32; P1.h1o = 512;
            P1.h2p = (s == SEQ) ? actDa : nullptr; P1.h2kt = 18; P1.h2o = 0;
            P1.xsrc = nullptr; P1.xdst = nullptr;
        }
        const int nz = (do0 && do1) ? 2 : 1;
        const int zbase = do0 ? 0 : 1;
        cell2_k<<<dim3(16, 16, nz), dim3(256), 0, stream>>>(P0, P1, zbase);
    }

    // ----- decoder: 8 steps x 3 launches -----
    for (int t = 0; t < HOR; ++t) {
        _Float16* dr = (t & 1) ? actDb : actDa;
        _Float16* dw = (t & 1) ? actDa : actDb;
        CellP PD = {};
        PD.Af = dr; PD.KTA = 18;
        PD.Bf = Wcd; PD.bias = bdi; PD.KT = 18;
        PD.cst = c1;
        PD.h1p = dw; PD.h1kt = 18; PD.h1o = 0;
        PD.h2p = nullptr; PD.xsrc = nullptr; PD.xdst = nullptr;
        cell2_k<<<dim3(16, 16, 1), dim3(256), 0, stream>>>(PD, PD, 0);
        expert_k<<<dim3(2, 16, 25), dim3(256), 0, stream>>>(dw, W1all, b1all, W2all, pe, t1);
        fin_k<<<dim3(8), dim3(256), 0, stream>>>(t1, gW2, gb2, pe, tb2, ib2, wb2, out, dw, t);
    }
}